// Round 1
// baseline (501.585 us; speedup 1.0000x reference)
//
#include <hip/hip_runtime.h>
#include <math.h>

// ---------------------------------------------------------------------------
// OurGMNCustom: graph-matching-network layer.
// Math simplifications (exact up to fp rounding):
//  * Xt2q[q] = elu(Xt@Wvc_t+b)[q] * [deg_cross_src(q)>0]   (softmax sums to 1)
//  * intra msg@Wv = U[e0]+V[e1]+b ; V[e1]+b segment-constant => out = segagg(U) + V + b
//  * intra attention logit: only s0[e0] matters (s1[e1]+b_a cancels in softmax)
//  * Q-mean term of Xt_merged is rank-1 -> folded into bias vector
// ---------------------------------------------------------------------------

__device__ __forceinline__ float elu1(float x) { return x > 0.f ? x : __expf(x) - 1.f; }

// ------------------------- GEMM: C = act(A1@W1 [+ A2@W2] + bias) -----------
// A: [M,128] row-major, W: [128,128] row-major, C: [M,128]. BM=32, BN=64.
__global__ __launch_bounds__(256) void gemm2_kernel(
    const float* __restrict__ A1, const float* __restrict__ W1,
    const float* __restrict__ A2, const float* __restrict__ W2,
    const int* __restrict__ rowmask2,     // pair-2 rows zeroed where mask==0
    const float* __restrict__ bias,       // [128] or null
    float* __restrict__ C, int act)
{
    __shared__ float As[128][36];   // transposed A tile, stride 36 breaks conflicts
    __shared__ float Ws[128][64];
    const int r0 = blockIdx.x * 32;
    const int c0 = blockIdx.y * 64;
    const int tid = threadIdx.x;
    const int tc = tid & 15;        // 16 col-groups of 4
    const int tr = tid >> 4;        // 16 row-groups of 2
    float acc[2][4] = {{0.f,0.f,0.f,0.f},{0.f,0.f,0.f,0.f}};

    for (int p = 0; p < 2; ++p) {
        const float* A = p ? A2 : A1;
        if (!A) break;
        const float* W = p ? W2 : W1;
        // stage A (transposed) : thread -> r = tid&31, kq = tid>>5
        {
            const int r = tid & 31, kq = tid >> 5;
            bool zero = false;
            if (p && rowmask2) zero = (rowmask2[r0 + r] == 0);
            #pragma unroll
            for (int j = 0; j < 4; ++j) {
                const int k = kq * 4 + j * 32;
                float4 v = *(const float4*)(A + (size_t)(r0 + r) * 128 + k);
                if (zero) v = make_float4(0.f, 0.f, 0.f, 0.f);
                As[k + 0][r] = v.x; As[k + 1][r] = v.y;
                As[k + 2][r] = v.z; As[k + 3][r] = v.w;
            }
            const int c4 = tid & 15, kk = tid >> 4;
            #pragma unroll
            for (int j = 0; j < 8; ++j) {
                const int k = kk + j * 16;
                float4 w = *(const float4*)(W + (size_t)k * 128 + c0 + c4 * 4);
                *(float4*)&Ws[k][c4 * 4] = w;
            }
        }
        __syncthreads();
        #pragma unroll 8
        for (int k = 0; k < 128; ++k) {
            const float2 a = *(const float2*)&As[k][tr * 2];
            const float4 w = *(const float4*)&Ws[k][tc * 4];
            acc[0][0] = fmaf(a.x, w.x, acc[0][0]);
            acc[0][1] = fmaf(a.x, w.y, acc[0][1]);
            acc[0][2] = fmaf(a.x, w.z, acc[0][2]);
            acc[0][3] = fmaf(a.x, w.w, acc[0][3]);
            acc[1][0] = fmaf(a.y, w.x, acc[1][0]);
            acc[1][1] = fmaf(a.y, w.y, acc[1][1]);
            acc[1][2] = fmaf(a.y, w.z, acc[1][2]);
            acc[1][3] = fmaf(a.y, w.w, acc[1][3]);
        }
        __syncthreads();
    }

    float4 bv = make_float4(0.f, 0.f, 0.f, 0.f);
    if (bias) bv = *(const float4*)(bias + c0 + tc * 4);
    #pragma unroll
    for (int i = 0; i < 2; ++i) {
        const int r = r0 + tr * 2 + i;
        float4 o;
        o.x = acc[i][0] + bv.x; o.y = acc[i][1] + bv.y;
        o.z = acc[i][2] + bv.z; o.w = acc[i][3] + bv.w;
        if (act) { o.x = elu1(o.x); o.y = elu1(o.y); o.z = elu1(o.z); o.w = elu1(o.w); }
        *(float4*)(C + (size_t)r * 128 + c0 + tc * 4) = o;
    }
}

// ------------------------- GEMV: out[i] = dot(A[i,:128], w[:128]) ----------
__global__ void gemv_kernel(const float* __restrict__ A, const float* __restrict__ w,
                            float* __restrict__ out, int M)
{
    const int wid = (int)((blockIdx.x * blockDim.x + threadIdx.x) >> 6);
    const int lane = threadIdx.x & 63;
    if (wid >= M) return;
    const float2 a = *(const float2*)(A + (size_t)wid * 128 + lane * 2);
    const float2 ww = *(const float2*)(w + lane * 2);
    float p = a.x * ww.x + a.y * ww.y;
    #pragma unroll
    for (int s = 32; s; s >>= 1) p += __shfl_xor(p, s, 64);
    if (lane == 0) out[wid] = p;
}

// ------------------------- cross logits: dot(Aq[src], At[dst]) -------------
__global__ void cross_logits_kernel(const float* __restrict__ Aq, const float* __restrict__ At,
                                    const int* __restrict__ src, const int* __restrict__ dst,
                                    float* __restrict__ logits, int E)
{
    const int nw = (int)((gridDim.x * blockDim.x) >> 6);
    const int wid = (int)((blockIdx.x * blockDim.x + threadIdx.x) >> 6);
    const int lane = threadIdx.x & 63;
    for (int e = wid; e < E; e += nw) {
        const int s = src[e], d = dst[e];
        const float2 a = *(const float2*)(Aq + (size_t)s * 128 + lane * 2);
        const float2 b = *(const float2*)(At + (size_t)d * 128 + lane * 2);
        float p = a.x * b.x + a.y * b.y;
        #pragma unroll
        for (int t = 32; t; t >>= 1) p += __shfl_xor(p, t, 64);
        if (lane == 0) logits[e] = p;
    }
}

// ------------------------- histograms --------------------------------------
__global__ void hist_kernel(const int* __restrict__ cs, const int* __restrict__ cd,
                            const int* __restrict__ et1, const int* __restrict__ eq1,
                            int* cnt_src, int* cnt_cd, int* cnt_t, int* cnt_q,
                            int EC, int ET, int EQ)
{
    const int e = blockIdx.x * blockDim.x + threadIdx.x;
    if (e < EC) { atomicAdd(&cnt_src[cs[e]], 1); atomicAdd(&cnt_cd[cd[e]], 1); }
    if (e < ET) atomicAdd(&cnt_t[et1[e]], 1);
    if (e < EQ) atomicAdd(&cnt_q[eq1[e]], 1);
}

// ------------------------- single-block exclusive scan (n = 8192) ----------
__global__ __launch_bounds__(1024) void scan_kernel(
    const int* __restrict__ c0, int* o0, int* u0, int n0,
    const int* __restrict__ c1, int* o1, int* u1, int n1,
    const int* __restrict__ c2, int* o2, int* u2, int n2)
{
    const int* cnt; int* offs; int* cur; int n;
    if (blockIdx.x == 0)      { cnt = c0; offs = o0; cur = u0; n = n0; }
    else if (blockIdx.x == 1) { cnt = c1; offs = o1; cur = u1; n = n1; }
    else                      { cnt = c2; offs = o2; cur = u2; n = n2; }
    __shared__ int sums[1024];
    const int tid = threadIdx.x;
    const int base = tid * 8;            // n == 8192
    int loc[8]; int s = 0;
    #pragma unroll
    for (int j = 0; j < 8; ++j) { loc[j] = s; s += cnt[base + j]; }
    sums[tid] = s;
    __syncthreads();
    for (int off = 1; off < 1024; off <<= 1) {
        int v = 0;
        if (tid >= off) v = sums[tid - off];
        __syncthreads();
        sums[tid] += v;
        __syncthreads();
    }
    const int ex = tid ? sums[tid - 1] : 0;
    #pragma unroll
    for (int j = 0; j < 8; ++j) { const int o = ex + loc[j]; offs[base + j] = o; cur[base + j] = o; }
    if (tid == 1023) offs[n] = sums[1023];
}

// ------------------------- CSR scatter -------------------------------------
__global__ void scatter_kernel(const int* __restrict__ cd, const int* __restrict__ et1,
                               const int* __restrict__ eq1,
                               int* cur_cd, int* ids_cd, int* cur_t, int* ids_t,
                               int* cur_q, int* ids_q, int EC, int ET, int EQ)
{
    const int e = blockIdx.x * blockDim.x + threadIdx.x;
    if (e < EC) { const int p = atomicAdd(&cur_cd[cd[e]], 1); ids_cd[p] = e; }
    if (e < ET) { const int p = atomicAdd(&cur_t[et1[e]], 1); ids_t[p] = e; }
    if (e < EQ) { const int p = atomicAdd(&cur_q[eq1[e]], 1); ids_q[p] = e; }
}

// ------------------------- column sums (for mean of Xq) --------------------
__global__ void colsum_kernel(const float* __restrict__ X, float* __restrict__ sum)
{
    const int c = threadIdx.x & 127;
    const int half = threadIdx.x >> 7;
    float s = 0.f;
    #pragma unroll 8
    for (int j = 0; j < 64; ++j) {
        const int r = blockIdx.x * 128 + half + 2 * j;
        s += X[(size_t)r * 128 + c];
    }
    atomicAdd(&sum[c], s);
}

// mt_extra[c] = b_mt[c] + sum_k (Qsum[k]/M) * W_mt[256+k][c]
__global__ void mt_extra_kernel(const float* __restrict__ Qsum, const float* __restrict__ Wmt,
                                const float* __restrict__ bmt, float* __restrict__ outv, int M)
{
    const int c = threadIdx.x;
    float acc = bmt[c];
    const float inv = 1.0f / (float)M;
    for (int k = 0; k < 128; ++k)
        acc = fmaf(Qsum[k] * inv, Wmt[(size_t)(256 + k) * 128 + c], acc);
    outv[c] = acc;
}

// ------------------------- segment softmax + weighted row aggregation ------
// One wave per segment. out[t] = (sum_e w_e * rows[esrc[e]]) / sum_e w_e  [+ extra[t]+ebias]
// w_e = exp(l_e - max), l_e = elogit[e] (cross) or nlogit[esrc[e]] (intra).
__global__ void seg_agg_kernel(
    const int* __restrict__ offs, const int* __restrict__ ids,
    const int* __restrict__ esrc,
    const float* __restrict__ elogit,   // per-edge logits or null
    const float* __restrict__ nlogit,   // per-source-node logits or null
    const float* __restrict__ rows,     // [*,128] gather table
    const float* __restrict__ extra,    // [*,128] or null (V term)
    const float* __restrict__ ebias,    // [128] or null
    float* __restrict__ out, int nseg)
{
    const int wid = (int)((blockIdx.x * blockDim.x + threadIdx.x) >> 6);
    const int lane = threadIdx.x & 63;
    if (wid >= nseg) return;
    const int lo = offs[wid], hi = offs[wid + 1];
    if (lo == hi) {
        *(float2*)(out + (size_t)wid * 128 + lane * 2) = make_float2(0.f, 0.f);
        return;
    }
    float m = -3.4e38f;
    for (int i = lo + lane; i < hi; i += 64) {
        const int e = ids[i];
        const float l = elogit ? elogit[e] : nlogit[esrc[e]];
        m = fmaxf(m, l);
    }
    #pragma unroll
    for (int t = 32; t; t >>= 1) m = fmaxf(m, __shfl_xor(m, t, 64));

    float s = 0.f, a0 = 0.f, a1 = 0.f;
    for (int i = lo; i < hi; ++i) {
        const int e = ids[i];
        const int src = esrc[e];
        const float l = elogit ? elogit[e] : nlogit[src];
        const float w = __expf(l - m);
        s += w;
        const float2 v = *(const float2*)(rows + (size_t)src * 128 + lane * 2);
        a0 = fmaf(w, v.x, a0);
        a1 = fmaf(w, v.y, a1);
    }
    const float inv = 1.f / s;
    float o0 = a0 * inv, o1 = a1 * inv;
    if (extra) {
        const float2 xv = *(const float2*)(extra + (size_t)wid * 128 + lane * 2);
        const float2 bv = *(const float2*)(ebias + lane * 2);
        o0 += xv.x + bv.x;
        o1 += xv.y + bv.y;
    }
    *(float2*)(out + (size_t)wid * 128 + lane * 2) = make_float2(o0, o1);
}

// ---------------------------------------------------------------------------
extern "C" void kernel_launch(void* const* d_in, const int* in_sizes, int n_in,
                              void* d_out, int out_size, void* d_ws, size_t ws_size,
                              hipStream_t stream)
{
    const float* Xq    = (const float*)d_in[0];
    const int*   eqidx = (const int*)d_in[1];
    const float* Xt    = (const float*)d_in[2];
    const int*   etidx = (const int*)d_in[3];
    const int*   cs    = (const int*)d_in[6];
    const int*   cd    = (const int*)d_in[7];
    const float* W_ac_q = (const float*)d_in[10]; const float* b_ac_q = (const float*)d_in[11];
    const float* W_ac_t = (const float*)d_in[12]; const float* b_ac_t = (const float*)d_in[13];
    const float* W_vc_q = (const float*)d_in[14]; const float* b_vc_q = (const float*)d_in[15];
    const float* W_vc_t = (const float*)d_in[16]; const float* b_vc_t = (const float*)d_in[17];
    const float* W_mq   = (const float*)d_in[18]; const float* b_mq   = (const float*)d_in[19];
    const float* W_mt   = (const float*)d_in[20]; const float* b_mt   = (const float*)d_in[21];
    const float* W_aq   = (const float*)d_in[22];
    const float* W_vq   = (const float*)d_in[24]; const float* b_vq   = (const float*)d_in[25];
    const float* W_at   = (const float*)d_in[26];
    const float* W_vt   = (const float*)d_in[28]; const float* b_vt   = (const float*)d_in[29];

    const int NQ = in_sizes[0] / 128;
    const int EQ = in_sizes[1] / 2;
    const int NT = in_sizes[2] / 128;
    const int ET = in_sizes[3] / 2;
    const int EC = in_sizes[6];

    const int* eq0 = eqidx;            const int* eq1 = eqidx + EQ;
    const int* et0 = etidx;            const int* et1 = etidx + ET;

    // ------------- workspace bump allocator (all 4-byte elements) ----------
    float* base = (float*)d_ws;
    size_t off = 0;
    auto alloc = [&](size_t n) { float* p = base + off; off += n; return p; };
    float* N0  = alloc((size_t)NQ * 128);   // Aq -> Xq2t -> Uq
    float* N1  = alloc((size_t)NT * 128);   // At -> Xt_merged
    float* N2  = alloc((size_t)NQ * 128);   // Vqc -> Xq_merged
    float* N3  = alloc((size_t)NT * 128);   // Vtc -> Ut
    float* L   = alloc((size_t)EC);         // cross logits
    float* st0v = alloc((size_t)NT);
    float* sq0v = alloc((size_t)NQ);
    float* mte = alloc(128);
    // zeroed region: [cnt_src, cnt_cd, cnt_t, cnt_q, Qsum] contiguous
    int* cnt_src = (int*)alloc((size_t)NQ);
    int* cnt_cd  = (int*)alloc((size_t)NT);
    int* cnt_t   = (int*)alloc((size_t)NT);
    int* cnt_q   = (int*)alloc((size_t)NQ);
    float* Qsum  = alloc(128);
    const size_t zero_bytes = ((size_t)(NQ + NT + NT + NQ) + 128) * 4;
    int* offs_cd = (int*)alloc((size_t)NT + 1);
    int* cur_cd  = (int*)alloc((size_t)NT);
    int* offs_t  = (int*)alloc((size_t)NT + 1);
    int* cur_t   = (int*)alloc((size_t)NT);
    int* offs_q  = (int*)alloc((size_t)NQ + 1);
    int* cur_q   = (int*)alloc((size_t)NQ);
    int* ids_cd  = (int*)alloc((size_t)EC);
    int* ids_t   = (int*)alloc((size_t)ET);
    int* ids_q   = (int*)alloc((size_t)EQ);

    float* Xq_out = (float*)d_out;                       // also Vq scratch
    float* Xt_out = (float*)d_out + (size_t)NQ * 128;    // also Vt scratch

    hipMemsetAsync(cnt_src, 0, zero_bytes, stream);

    int Emax = EC > ET ? EC : ET; if (EQ > Emax) Emax = EQ;
    const int eb = (Emax + 255) / 256;

    // CSR build + degree counts
    hist_kernel<<<eb, 256, 0, stream>>>(cs, cd, et1, eq1, cnt_src, cnt_cd, cnt_t, cnt_q, EC, ET, EQ);
    scan_kernel<<<3, 1024, 0, stream>>>(cnt_cd, offs_cd, cur_cd, NT,
                                        cnt_t, offs_t, cur_t, NT,
                                        cnt_q, offs_q, cur_q, NQ);
    scatter_kernel<<<eb, 256, 0, stream>>>(cd, et1, eq1, cur_cd, ids_cd, cur_t, ids_t, cur_q, ids_q,
                                           EC, ET, EQ);
    colsum_kernel<<<NQ / 128, 256, 0, stream>>>(Xq, Qsum);

    const dim3 gq(NQ / 32, 2), gt(NT / 32, 2);
    // Aq = elu(Xq@W_ac_q + b), At = elu(Xt@W_ac_t + b)
    gemm2_kernel<<<gq, 256, 0, stream>>>(Xq, W_ac_q, nullptr, nullptr, nullptr, b_ac_q, N0, 1);
    gemm2_kernel<<<gt, 256, 0, stream>>>(Xt, W_ac_t, nullptr, nullptr, nullptr, b_ac_t, N1, 1);
    cross_logits_kernel<<<2048, 256, 0, stream>>>(N0, N1, cs, cd, L, EC);
    // Vqc, Vtc
    gemm2_kernel<<<gq, 256, 0, stream>>>(Xq, W_vc_q, nullptr, nullptr, nullptr, b_vc_q, N2, 1);
    gemm2_kernel<<<gt, 256, 0, stream>>>(Xt, W_vc_t, nullptr, nullptr, nullptr, b_vc_t, N3, 1);
    // Xq2t (segments = cross_dst, rows = Vqc[cross_src]) -> N0
    seg_agg_kernel<<<(NT + 3) / 4, 256, 0, stream>>>(offs_cd, ids_cd, cs, L, nullptr, N2,
                                                     nullptr, nullptr, N0, NT);
    // Xq_merged = Xq@Wmq_top + (Vtc masked by deg_src)@Wmq_bot + b_mq -> N2
    gemm2_kernel<<<gq, 256, 0, stream>>>(Xq, W_mq, N3, W_mq + 128 * 128, cnt_src, b_mq, N2, 0);
    // folded bias for Xt_merged (b_mt + mean(Xq)@Wmt[256:384])
    mt_extra_kernel<<<1, 128, 0, stream>>>(Qsum, W_mt, b_mt, mte, NQ);
    // Xt_merged = Xt@Wmt0 + Xq2t@Wmt1 + mte -> N1
    gemm2_kernel<<<gt, 256, 0, stream>>>(Xt, W_mt, N0, W_mt + 128 * 128, nullptr, mte, N1, 0);
    // attention score vectors (only the e0 half matters; e1 half cancels in softmax)
    gemv_kernel<<<NT / 4, 256, 0, stream>>>(N1, W_at, st0v, NT);
    gemv_kernel<<<NQ / 4, 256, 0, stream>>>(N2, W_aq, sq0v, NQ);
    // Ut -> N3, Vt -> Xt_out (scratch), Uq -> N0, Vq -> Xq_out (scratch)
    gemm2_kernel<<<gt, 256, 0, stream>>>(N1, W_vt, nullptr, nullptr, nullptr, nullptr, N3, 0);
    gemm2_kernel<<<gt, 256, 0, stream>>>(N1, W_vt + 128 * 128, nullptr, nullptr, nullptr, nullptr, Xt_out, 0);
    gemm2_kernel<<<gq, 256, 0, stream>>>(N2, W_vq, nullptr, nullptr, nullptr, nullptr, N0, 0);
    gemm2_kernel<<<gq, 256, 0, stream>>>(N2, W_vq + 128 * 128, nullptr, nullptr, nullptr, nullptr, Xq_out, 0);
    // final intra aggregations (out aliases V scratch row-wise: read-then-write per wave, safe)
    seg_agg_kernel<<<(NT + 3) / 4, 256, 0, stream>>>(offs_t, ids_t, et0, nullptr, st0v, N3,
                                                     Xt_out, b_vt, Xt_out, NT);
    seg_agg_kernel<<<(NQ + 3) / 4, 256, 0, stream>>>(offs_q, ids_q, eq0, nullptr, sq0v, N0,
                                                     Xq_out, b_vq, Xq_out, NQ);
}

// Round 2
// 353.746 us; speedup vs baseline: 1.4179x; 1.4179x over previous
//
#include <hip/hip_runtime.h>
#include <math.h>

// ---------------------------------------------------------------------------
// OurGMNCustom round 2.
// Math simplifications (validated in round 1, absmax 2e-3):
//  * Xt2q[q] = elu(Xt@Wvc_t+b)[q] * [deg_cross_src(q)>0]
//  * intra msg@Wv = U[e0]+V[e1]+b ; V[e1]+b segment-constant
//  * intra attention logit: only s0[e0] matters
//  * Q-mean term folded into bias
// Round-2 changes:
//  * CSR build with ZERO global atomics (LDS-privatized hist + hierarchical
//    prefix + deterministic scatter) - old hist/scatter were bound by
//    atomic write-through (~650 GB/s, 52+45 us).
//  * CSR payload: cross stores (src,logit) pairs; intra stores e0 node id
//    directly - removes scattered indirections in seg_agg.
//  * GEMM: BM=128/BN=64/BK=32, 8x4/thread (0.375 LDS dw/FMA -> VALU-bound),
//    12 launches fused into 3.
// ---------------------------------------------------------------------------

#define NBIN 8192          // == NQ == NT for this problem
#define NB   256           // histogram blocks
#define NG   16            // k-groups (NB/16)

__device__ __forceinline__ float elu1(float x) { return x > 0.f ? x : __expf(x) - 1.f; }

// ------------------------- fused GEMM --------------------------------------
struct GemmJob {
    const float* A0; const float* A1; const int* rowmask1;
    const float* W00; const float* W01;   // pass0 weight for out0/out1
    const float* W10; const float* W11;   // pass1 weight for out0/out1
    const float* bias0; const float* bias1;
    float* C0; float* C1;
    int act;
};

__global__ __launch_bounds__(256) void gemm_big(GemmJob j0, GemmJob j1)
{
    const GemmJob j = blockIdx.z ? j1 : j0;
    const int out = blockIdx.y >> 1;
    const int c0 = (blockIdx.y & 1) * 64;
    const int r0 = blockIdx.x * 128;
    __shared__ float As[32][132];
    __shared__ float Ws[32][64];
    const int tid = threadIdx.x;
    const int tr = tid >> 4, tc = tid & 15;
    float acc[8][4] = {};

    const float* A_pass[2] = { j.A0, j.A1 };
    const float* W_pass[2] = { out ? j.W01 : j.W00, out ? j.W11 : j.W10 };

    for (int p = 0; p < 2; ++p) {
        const float* A = A_pass[p];
        if (!A) break;
        const float* W = W_pass[p];
        const int* rm = (p == 1) ? j.rowmask1 : nullptr;
        for (int kc = 0; kc < 4; ++kc) {
            // stage A tile (transposed) : 128 rows x 32 k
            {
                const int k4 = (tid & 7) * 4;
                const int rb = tid >> 3;          // 0..31
                #pragma unroll
                for (int i = 0; i < 4; ++i) {
                    const int r = rb + 32 * i;
                    float4 v = *(const float4*)(A + (size_t)(r0 + r) * 128 + kc * 32 + k4);
                    if (rm && rm[r0 + r] == 0) v = make_float4(0.f, 0.f, 0.f, 0.f);
                    As[k4 + 0][r] = v.x; As[k4 + 1][r] = v.y;
                    As[k4 + 2][r] = v.z; As[k4 + 3][r] = v.w;
                }
                const int cc = (tid & 15) * 4;
                const int kb = tid >> 4;          // 0..15
                #pragma unroll
                for (int i = 0; i < 2; ++i) {
                    const int k = kb + 16 * i;
                    *(float4*)&Ws[k][cc] = *(const float4*)(W + (size_t)(kc * 32 + k) * 128 + c0 + cc);
                }
            }
            __syncthreads();
            #pragma unroll 4
            for (int k = 0; k < 32; ++k) {
                const float4 a0 = *(const float4*)&As[k][tr * 4];
                const float4 a1 = *(const float4*)&As[k][64 + tr * 4];
                const float4 w  = *(const float4*)&Ws[k][tc * 4];
                const float ar[8] = {a0.x, a0.y, a0.z, a0.w, a1.x, a1.y, a1.z, a1.w};
                #pragma unroll
                for (int i = 0; i < 8; ++i) {
                    acc[i][0] = fmaf(ar[i], w.x, acc[i][0]);
                    acc[i][1] = fmaf(ar[i], w.y, acc[i][1]);
                    acc[i][2] = fmaf(ar[i], w.z, acc[i][2]);
                    acc[i][3] = fmaf(ar[i], w.w, acc[i][3]);
                }
            }
            __syncthreads();
        }
    }

    float4 bv = make_float4(0.f, 0.f, 0.f, 0.f);
    const float* bias = out ? j.bias1 : j.bias0;
    if (bias) bv = *(const float4*)(bias + c0 + tc * 4);
    float* C = out ? j.C1 : j.C0;
    #pragma unroll
    for (int i = 0; i < 8; ++i) {
        const int row = r0 + (i >> 2) * 64 + tr * 4 + (i & 3);
        float4 o;
        o.x = acc[i][0] + bv.x; o.y = acc[i][1] + bv.y;
        o.z = acc[i][2] + bv.z; o.w = acc[i][3] + bv.w;
        if (j.act) { o.x = elu1(o.x); o.y = elu1(o.y); o.z = elu1(o.z); o.w = elu1(o.w); }
        *(float4*)(C + (size_t)row * 128 + c0 + tc * 4) = o;
    }
}

// ------------------------- fused GEMV --------------------------------------
__global__ void gemv2_kernel(const float* __restrict__ A0, const float* __restrict__ w0,
                             float* __restrict__ o0, int M0,
                             const float* __restrict__ A1, const float* __restrict__ w1,
                             float* __restrict__ o1, int M1)
{
    const int wid = (int)((blockIdx.x * blockDim.x + threadIdx.x) >> 6);
    const int lane = threadIdx.x & 63;
    const float* A; const float* w; float* o; int row;
    if (wid < M0) { A = A0; w = w0; o = o0; row = wid; }
    else if (wid < M0 + M1) { A = A1; w = w1; o = o1; row = wid - M0; }
    else return;
    const float2 a = *(const float2*)(A + (size_t)row * 128 + lane * 2);
    const float2 ww = *(const float2*)(w + lane * 2);
    float p = a.x * ww.x + a.y * ww.y;
    #pragma unroll
    for (int s = 32; s; s >>= 1) p += __shfl_xor(p, s, 64);
    if (lane == 0) o[row] = p;
}

// ------------------------- cross logits ------------------------------------
__global__ void cross_logits_kernel(const float* __restrict__ Aq, const float* __restrict__ At,
                                    const int* __restrict__ src, const int* __restrict__ dst,
                                    float* __restrict__ logits, int E)
{
    const int nw = (int)((gridDim.x * blockDim.x) >> 6);
    const int wid = (int)((blockIdx.x * blockDim.x + threadIdx.x) >> 6);
    const int lane = threadIdx.x & 63;
    for (int e = wid; e < E; e += nw) {
        const int s = src[e], d = dst[e];
        const float2 a = *(const float2*)(Aq + (size_t)s * 128 + lane * 2);
        const float2 b = *(const float2*)(At + (size_t)d * 128 + lane * 2);
        float p = a.x * b.x + a.y * b.y;
        #pragma unroll
        for (int t = 32; t; t >>= 1) p += __shfl_xor(p, t, 64);
        if (lane == 0) logits[e] = p;
    }
}

// ------------------------- CSR build (atomic-free) -------------------------
// K1: per-block LDS histogram -> partial[arr][block][bin] (ushort)
__global__ __launch_bounds__(256) void hist_priv(
    const int* __restrict__ cs, const int* __restrict__ cd,
    const int* __restrict__ et1, const int* __restrict__ eq1,
    int* __restrict__ mask_src, unsigned short* __restrict__ partial,
    int EC, int ET, int EQ)
{
    __shared__ int h[NBIN];
    const int k = blockIdx.x, tid = threadIdx.x;
    const int* idxs[3] = { cd, et1, eq1 };
    const int Es[3] = { EC, ET, EQ };
    for (int a = 0; a < 3; ++a) {
        for (int b = tid; b < NBIN; b += 256) h[b] = 0;
        __syncthreads();
        const int E = Es[a];
        const int per = (E + NB - 1) / NB;
        const int lo = k * per;
        const int hi = min(E, lo + per);
        const int* idx = idxs[a];
        for (int e = lo + tid; e < hi; e += 256) {
            atomicAdd(&h[idx[e]], 1);                 // LDS atomic
            if (a == 0) mask_src[cs[e]] = 1;          // benign race
        }
        __syncthreads();
        unsigned short* P = partial + ((size_t)a * NB + k) * NBIN;
        for (int b = tid; b < NBIN; b += 256) P[b] = (unsigned short)h[b];
        __syncthreads();
    }
}

// K2a: sub[arr][g][bin] = sum over 16 blocks of partial
__global__ void subsum_kernel(const unsigned short* __restrict__ partial,
                              unsigned short* __restrict__ sub)
{
    const int bin = blockIdx.x * 256 + threadIdx.x;
    const int g = blockIdx.y, a = blockIdx.z;
    const unsigned short* P = partial + (size_t)a * NB * NBIN;
    int s = 0;
    for (int k = g * 16; k < g * 16 + 16; ++k) s += P[(size_t)k * NBIN + bin];
    sub[((size_t)a * NG + g) * NBIN + bin] = (unsigned short)s;
}

// K2b: exclusive scan of sub along g (in place), total -> cnt
__global__ void subscan_kernel(unsigned short* __restrict__ sub, int* __restrict__ cnt)
{
    const int bin = blockIdx.x * 256 + threadIdx.x;
    const int a = blockIdx.y;
    unsigned short* S = sub + (size_t)a * NG * NBIN;
    int s = 0;
    for (int g = 0; g < NG; ++g) {
        const int v = S[(size_t)g * NBIN + bin];
        S[(size_t)g * NBIN + bin] = (unsigned short)s;
        s += v;
    }
    cnt[a * NBIN + bin] = s;
}

// K3: per-array exclusive scan over 8192 bins (3 blocks)
__global__ __launch_bounds__(1024) void scan3_kernel(const int* __restrict__ cnt, int* __restrict__ offs)
{
    const int b = blockIdx.x;
    const int* c = cnt + (size_t)b * NBIN;
    int* o = offs + (size_t)b * (NBIN + 1);
    __shared__ int sums[1024];
    const int tid = threadIdx.x;
    int loc[8]; int s = 0;
    #pragma unroll
    for (int j = 0; j < 8; ++j) { loc[j] = s; s += c[tid * 8 + j]; }
    sums[tid] = s;
    __syncthreads();
    for (int off = 1; off < 1024; off <<= 1) {
        int v = 0;
        if (tid >= off) v = sums[tid - off];
        __syncthreads();
        sums[tid] += v;
        __syncthreads();
    }
    const int ex = tid ? sums[tid - 1] : 0;
    #pragma unroll
    for (int j = 0; j < 8; ++j) o[tid * 8 + j] = ex + loc[j];
    if (tid == 1023) o[NBIN] = sums[1023];
}

// K2c: expand partial (in place) to within-bin exclusive prefix before block k
__global__ void expand_kernel(unsigned short* __restrict__ partial,
                              const unsigned short* __restrict__ sub)
{
    const int bin = blockIdx.x * 256 + threadIdx.x;
    const int g = blockIdx.y, a = blockIdx.z;
    int s = sub[((size_t)a * NG + g) * NBIN + bin];
    unsigned short* P = partial + (size_t)a * NB * NBIN;
    for (int k = g * 16; k < g * 16 + 16; ++k) {
        const int p = P[(size_t)k * NBIN + bin];
        P[(size_t)k * NBIN + bin] = (unsigned short)s;
        s += p;
    }
}

// K5: deterministic scatter (LDS cursors, no global atomics)
__global__ __launch_bounds__(256) void scatter_det(
    const int* __restrict__ cs, const int* __restrict__ cd, const float* __restrict__ L,
    const int* __restrict__ et0, const int* __restrict__ et1,
    const int* __restrict__ eq0, const int* __restrict__ eq1,
    const unsigned short* __restrict__ partial, const int* __restrict__ offs,
    float2* __restrict__ pairs_cd, int* __restrict__ ids_t, int* __restrict__ ids_q,
    int EC, int ET, int EQ)
{
    __shared__ int cur[NBIN];
    const int k = blockIdx.x, tid = threadIdx.x;
    const int Es[3] = { EC, ET, EQ };
    for (int a = 0; a < 3; ++a) {
        const unsigned short* P = partial + ((size_t)a * NB + k) * NBIN;
        const int* off = offs + (size_t)a * (NBIN + 1);
        for (int b = tid; b < NBIN; b += 256) cur[b] = off[b] + (int)P[b];
        __syncthreads();
        const int E = Es[a];
        const int per = (E + NB - 1) / NB;
        const int lo = k * per;
        const int hi = min(E, lo + per);
        if (a == 0) {
            for (int e = lo + tid; e < hi; e += 256) {
                const int pos = atomicAdd(&cur[cd[e]], 1);    // LDS atomic
                pairs_cd[pos] = make_float2(__int_as_float(cs[e]), L[e]);
            }
        } else if (a == 1) {
            for (int e = lo + tid; e < hi; e += 256) {
                const int pos = atomicAdd(&cur[et1[e]], 1);
                ids_t[pos] = et0[e];
            }
        } else {
            for (int e = lo + tid; e < hi; e += 256) {
                const int pos = atomicAdd(&cur[eq1[e]], 1);
                ids_q[pos] = eq0[e];
            }
        }
        __syncthreads();
    }
}

// ------------------------- column sums + folded bias -----------------------
__global__ void colsum_kernel(const float* __restrict__ X, float* __restrict__ sum)
{
    const int c = threadIdx.x & 127;
    const int half = threadIdx.x >> 7;
    float s = 0.f;
    #pragma unroll 8
    for (int j = 0; j < 64; ++j) {
        const int r = blockIdx.x * 128 + half + 2 * j;
        s += X[(size_t)r * 128 + c];
    }
    atomicAdd(&sum[c], s);
}

__global__ void mt_extra_kernel(const float* __restrict__ Qsum, const float* __restrict__ Wmt,
                                const float* __restrict__ bmt, float* __restrict__ outv, int M)
{
    const int c = threadIdx.x;
    float acc = bmt[c];
    const float inv = 1.0f / (float)M;
    for (int k = 0; k < 128; ++k)
        acc = fmaf(Qsum[k] * inv, Wmt[(size_t)(256 + k) * 128 + c], acc);
    outv[c] = acc;
}

// ------------------------- segment softmax aggregations --------------------
// cross: pairs = (src_bits, logit) per CSR slot
__global__ void seg_agg_cross(const int* __restrict__ offs, const float2* __restrict__ pairs,
                              const float* __restrict__ rows, float* __restrict__ out, int nseg)
{
    const int wid = (int)((blockIdx.x * blockDim.x + threadIdx.x) >> 6);
    const int lane = threadIdx.x & 63;
    if (wid >= nseg) return;
    const int lo = offs[wid], hi = offs[wid + 1];
    if (lo == hi) {
        *(float2*)(out + (size_t)wid * 128 + lane * 2) = make_float2(0.f, 0.f);
        return;
    }
    float m = -3.4e38f;
    for (int i = lo + lane; i < hi; i += 64) m = fmaxf(m, pairs[i].y);
    #pragma unroll
    for (int t = 32; t; t >>= 1) m = fmaxf(m, __shfl_xor(m, t, 64));
    float s = 0.f, a0 = 0.f, a1 = 0.f;
    for (int i = lo; i < hi; ++i) {
        const float2 pr = pairs[i];
        const int src = __float_as_int(pr.x);
        const float w = __expf(pr.y - m);
        s += w;
        const float2 v = *(const float2*)(rows + (size_t)src * 128 + lane * 2);
        a0 = fmaf(w, v.x, a0);
        a1 = fmaf(w, v.y, a1);
    }
    const float inv = 1.f / s;
    *(float2*)(out + (size_t)wid * 128 + lane * 2) = make_float2(a0 * inv, a1 * inv);
}

// intra (fused t/q via blockIdx.y): ids hold source NODE directly
__global__ void seg_agg_intra(
    const int* ot, const int* it, const float* nlt, const float* rt,
    const float* xt, const float* ebt, float* outt,
    const int* oq, const int* iq, const float* nlq, const float* rq,
    const float* xq, const float* ebq, float* outq, int nseg)
{
    const int* offs; const int* ids; const float* nl; const float* rows;
    const float* extra; const float* eb; float* out;
    if (blockIdx.y == 0) { offs = ot; ids = it; nl = nlt; rows = rt; extra = xt; eb = ebt; out = outt; }
    else                 { offs = oq; ids = iq; nl = nlq; rows = rq; extra = xq; eb = ebq; out = outq; }
    const int wid = (int)((blockIdx.x * blockDim.x + threadIdx.x) >> 6);
    const int lane = threadIdx.x & 63;
    if (wid >= nseg) return;
    const int lo = offs[wid], hi = offs[wid + 1];
    if (lo == hi) {
        *(float2*)(out + (size_t)wid * 128 + lane * 2) = make_float2(0.f, 0.f);
        return;
    }
    float m = -3.4e38f;
    for (int i = lo + lane; i < hi; i += 64) m = fmaxf(m, nl[ids[i]]);
    #pragma unroll
    for (int t = 32; t; t >>= 1) m = fmaxf(m, __shfl_xor(m, t, 64));
    float s = 0.f, a0 = 0.f, a1 = 0.f;
    for (int i = lo; i < hi; ++i) {
        const int src = ids[i];
        const float w = __expf(nl[src] - m);
        s += w;
        const float2 v = *(const float2*)(rows + (size_t)src * 128 + lane * 2);
        a0 = fmaf(w, v.x, a0);
        a1 = fmaf(w, v.y, a1);
    }
    const float inv = 1.f / s;
    const float2 xv = *(const float2*)(extra + (size_t)wid * 128 + lane * 2);
    const float2 bv = *(const float2*)(eb + lane * 2);
    *(float2*)(out + (size_t)wid * 128 + lane * 2) =
        make_float2(a0 * inv + xv.x + bv.x, a1 * inv + xv.y + bv.y);
}

// ---------------------------------------------------------------------------
extern "C" void kernel_launch(void* const* d_in, const int* in_sizes, int n_in,
                              void* d_out, int out_size, void* d_ws, size_t ws_size,
                              hipStream_t stream)
{
    const float* Xq    = (const float*)d_in[0];
    const int*   eqidx = (const int*)d_in[1];
    const float* Xt    = (const float*)d_in[2];
    const int*   etidx = (const int*)d_in[3];
    const int*   cs    = (const int*)d_in[6];
    const int*   cd    = (const int*)d_in[7];
    const float* W_ac_q = (const float*)d_in[10]; const float* b_ac_q = (const float*)d_in[11];
    const float* W_ac_t = (const float*)d_in[12]; const float* b_ac_t = (const float*)d_in[13];
    const float* W_vc_q = (const float*)d_in[14]; const float* b_vc_q = (const float*)d_in[15];
    const float* W_vc_t = (const float*)d_in[16]; const float* b_vc_t = (const float*)d_in[17];
    const float* W_mq   = (const float*)d_in[18]; const float* b_mq   = (const float*)d_in[19];
    const float* W_mt   = (const float*)d_in[20]; const float* b_mt   = (const float*)d_in[21];
    const float* W_aq   = (const float*)d_in[22];
    const float* W_vq   = (const float*)d_in[24]; const float* b_vq   = (const float*)d_in[25];
    const float* W_at   = (const float*)d_in[26];
    const float* W_vt   = (const float*)d_in[28]; const float* b_vt   = (const float*)d_in[29];

    const int NQ = in_sizes[0] / 128;
    const int EQ = in_sizes[1] / 2;
    const int NT = in_sizes[2] / 128;
    const int ET = in_sizes[3] / 2;
    const int EC = in_sizes[6];

    const int* eq0 = eqidx;  const int* eq1 = eqidx + EQ;
    const int* et0 = etidx;  const int* et1 = etidx + ET;

    // ------------- workspace bump allocator --------------------------------
    float* base = (float*)d_ws;
    size_t off = 0;
    auto alloc = [&](size_t n) { float* p = base + off; off += n; return p; };
    float* N0 = alloc((size_t)NQ * 128);   // Aq -> Xq2t -> Uq
    float* N1 = alloc((size_t)NT * 128);   // At -> Xt_merged
    float* N2 = alloc((size_t)NQ * 128);   // Vqc -> Xq_merged
    float* N3 = alloc((size_t)NT * 128);   // Vtc -> Ut
    float* L  = alloc((size_t)EC);
    float* st0v = alloc((size_t)NT);
    float* sq0v = alloc((size_t)NQ);
    float* mte  = alloc(128);
    int* mask_src = (int*)alloc((size_t)NQ);        // memset region start
    float* Qsum   = alloc(128);
    const size_t zero_bytes = ((size_t)NQ + 128) * 4;
    int* cnt  = (int*)alloc((size_t)3 * NBIN);
    int* offs = (int*)alloc((size_t)3 * (NBIN + 1));
    unsigned short* partial = (unsigned short*)alloc((size_t)3 * NB * NBIN / 2);
    unsigned short* sub     = (unsigned short*)alloc((size_t)3 * NG * NBIN / 2);
    float2* pairs_cd = (float2*)alloc((size_t)EC * 2);
    int* ids_t = (int*)alloc((size_t)ET);
    int* ids_q = (int*)alloc((size_t)EQ);

    float* Xq_out = (float*)d_out;
    float* Xt_out = (float*)d_out + (size_t)NQ * 128;

    const int* offs_cd = offs;
    const int* offs_t  = offs + (NBIN + 1);
    const int* offs_q  = offs + 2 * (NBIN + 1);

    hipMemsetAsync(mask_src, 0, zero_bytes, stream);

    // ---- CSR build (atomic-free) ----
    hist_priv<<<NB, 256, 0, stream>>>(cs, cd, et1, eq1, mask_src, partial, EC, ET, EQ);
    subsum_kernel<<<dim3(NBIN / 256, NG, 3), 256, 0, stream>>>(partial, sub);
    subscan_kernel<<<dim3(NBIN / 256, 3), 256, 0, stream>>>(sub, cnt);
    scan3_kernel<<<3, 1024, 0, stream>>>(cnt, offs);
    expand_kernel<<<dim3(NBIN / 256, NG, 3), 256, 0, stream>>>(partial, sub);

    colsum_kernel<<<NQ / 128, 256, 0, stream>>>(Xq, Qsum);

    // ---- G12: Xq -> [Aq|Vqc], Xt -> [At|Vtc] ----
    GemmJob jq{}, jt{};
    jq.A0 = Xq; jq.W00 = W_ac_q; jq.W01 = W_vc_q; jq.bias0 = b_ac_q; jq.bias1 = b_vc_q;
    jq.C0 = N0; jq.C1 = N2; jq.act = 1;
    jt.A0 = Xt; jt.W00 = W_ac_t; jt.W01 = W_vc_t; jt.bias0 = b_ac_t; jt.bias1 = b_vc_t;
    jt.C0 = N1; jt.C1 = N3; jt.act = 1;
    gemm_big<<<dim3(NQ / 128, 4, 2), 256, 0, stream>>>(jq, jt);

    cross_logits_kernel<<<2048, 256, 0, stream>>>(N0, N1, cs, cd, L, EC);

    // ---- scatter (packs (src,logit) pairs / source nodes) ----
    scatter_det<<<NB, 256, 0, stream>>>(cs, cd, L, et0, et1, eq0, eq1, partial, offs,
                                        pairs_cd, ids_t, ids_q, EC, ET, EQ);

    // ---- Xq2t -> N0 (overwrites Aq) ----
    seg_agg_cross<<<(NT + 3) / 4, 256, 0, stream>>>(offs_cd, pairs_cd, N2, N0, NT);

    mt_extra_kernel<<<1, 128, 0, stream>>>(Qsum, W_mt, b_mt, mte, NQ);

    // ---- G56: merged builds ----
    GemmJob mq{}, mt{};
    mq.A0 = Xq; mq.W00 = W_mq;               mq.A1 = N3; mq.W10 = W_mq + 128 * 128;
    mq.rowmask1 = mask_src; mq.bias0 = b_mq; mq.C0 = N2; mq.act = 0;
    mt.A0 = Xt; mt.W00 = W_mt;               mt.A1 = N0; mt.W10 = W_mt + 128 * 128;
    mt.bias0 = mte; mt.C0 = N1; mt.act = 0;
    gemm_big<<<dim3(NQ / 128, 2, 2), 256, 0, stream>>>(mq, mt);

    // ---- attention score vectors ----
    gemv2_kernel<<<(NT + NQ) / 4, 256, 0, stream>>>(N1, W_at, st0v, NT, N2, W_aq, sq0v, NQ);

    // ---- G34: N1 -> [Ut|Vt], N2 -> [Uq|Vq] ----
    GemmJob ut{}, uq{};
    ut.A0 = N1; ut.W00 = W_vt; ut.W01 = W_vt + 128 * 128; ut.C0 = N3; ut.C1 = Xt_out; ut.act = 0;
    uq.A0 = N2; uq.W00 = W_vq; uq.W01 = W_vq + 128 * 128; uq.C0 = N0; uq.C1 = Xq_out; uq.act = 0;
    gemm_big<<<dim3(NT / 128, 4, 2), 256, 0, stream>>>(ut, uq);

    // ---- final intra aggregations (fused t+q) ----
    seg_agg_intra<<<dim3((NT + 3) / 4, 2), 256, 0, stream>>>(
        offs_t, ids_t, st0v, N3, Xt_out, b_vt, Xt_out,
        offs_q, ids_q, sq0v, N0, Xq_out, b_vq, Xq_out, NT);
}

// Round 3
// 290.004 us; speedup vs baseline: 1.7296x; 1.2198x over previous
//
#include <hip/hip_runtime.h>
#include <math.h>

// ---------------------------------------------------------------------------
// OurGMNCustom round 3.
// Math simplifications (validated: absmax 2e-3 vs 2e-2 threshold):
//  * Xt2q[q] = elu(Xt@Wvc_t+b)[q] * [deg_cross_src(q)>0]
//  * intra msg@Wv = U[e0]+V[e1]+b ; V[e1]+b segment-constant
//  * intra attention logit: only s0[e0] matters
//  * Q-mean term folded into bias
// Round-3 changes (seg_agg kernels were latency-bound: 1 edge/iter dependent
// chain, VALUBusy 22.6%):
//  * seg_agg_*: chunk-of-64 batched edge loads, shfl broadcast, 2-edge-
//    parallel half-wave float4 gathers, unroll x4 -> ~8 loads in flight.
//  * cross_logits FUSED into seg_agg_cross (At row in LDS, lane-per-edge
//    dot pass with LDS logit cache) -> one ~1KB/edge kernel eliminated.
//  * scatter payload for cross: plain src int (no (src,logit) pairs).
// ---------------------------------------------------------------------------

#define NBIN 8192          // == NQ == NT for this problem
#define NB   256           // histogram blocks
#define NG   16            // k-groups (NB/16)
#define DEGCAP 256         // per-segment LDS logit cache

__device__ __forceinline__ float elu1(float x) { return x > 0.f ? x : __expf(x) - 1.f; }

// ------------------------- fused GEMM --------------------------------------
struct GemmJob {
    const float* A0; const float* A1; const int* rowmask1;
    const float* W00; const float* W01;   // pass0 weight for out0/out1
    const float* W10; const float* W11;   // pass1 weight for out0/out1
    const float* bias0; const float* bias1;
    float* C0; float* C1;
    int act;
};

__global__ __launch_bounds__(256) void gemm_big(GemmJob j0, GemmJob j1)
{
    const GemmJob j = blockIdx.z ? j1 : j0;
    const int out = blockIdx.y >> 1;
    const int c0 = (blockIdx.y & 1) * 64;
    const int r0 = blockIdx.x * 128;
    __shared__ float As[32][132];
    __shared__ float Ws[32][64];
    const int tid = threadIdx.x;
    const int tr = tid >> 4, tc = tid & 15;
    float acc[8][4] = {};

    const float* A_pass[2] = { j.A0, j.A1 };
    const float* W_pass[2] = { out ? j.W01 : j.W00, out ? j.W11 : j.W10 };

    for (int p = 0; p < 2; ++p) {
        const float* A = A_pass[p];
        if (!A) break;
        const float* W = W_pass[p];
        const int* rm = (p == 1) ? j.rowmask1 : nullptr;
        for (int kc = 0; kc < 4; ++kc) {
            {
                const int k4 = (tid & 7) * 4;
                const int rb = tid >> 3;          // 0..31
                #pragma unroll
                for (int i = 0; i < 4; ++i) {
                    const int r = rb + 32 * i;
                    float4 v = *(const float4*)(A + (size_t)(r0 + r) * 128 + kc * 32 + k4);
                    if (rm && rm[r0 + r] == 0) v = make_float4(0.f, 0.f, 0.f, 0.f);
                    As[k4 + 0][r] = v.x; As[k4 + 1][r] = v.y;
                    As[k4 + 2][r] = v.z; As[k4 + 3][r] = v.w;
                }
                const int cc = (tid & 15) * 4;
                const int kb = tid >> 4;          // 0..15
                #pragma unroll
                for (int i = 0; i < 2; ++i) {
                    const int k = kb + 16 * i;
                    *(float4*)&Ws[k][cc] = *(const float4*)(W + (size_t)(kc * 32 + k) * 128 + c0 + cc);
                }
            }
            __syncthreads();
            #pragma unroll 4
            for (int k = 0; k < 32; ++k) {
                const float4 a0 = *(const float4*)&As[k][tr * 4];
                const float4 a1 = *(const float4*)&As[k][64 + tr * 4];
                const float4 w  = *(const float4*)&Ws[k][tc * 4];
                const float ar[8] = {a0.x, a0.y, a0.z, a0.w, a1.x, a1.y, a1.z, a1.w};
                #pragma unroll
                for (int i = 0; i < 8; ++i) {
                    acc[i][0] = fmaf(ar[i], w.x, acc[i][0]);
                    acc[i][1] = fmaf(ar[i], w.y, acc[i][1]);
                    acc[i][2] = fmaf(ar[i], w.z, acc[i][2]);
                    acc[i][3] = fmaf(ar[i], w.w, acc[i][3]);
                }
            }
            __syncthreads();
        }
    }

    float4 bv = make_float4(0.f, 0.f, 0.f, 0.f);
    const float* bias = out ? j.bias1 : j.bias0;
    if (bias) bv = *(const float4*)(bias + c0 + tc * 4);
    float* C = out ? j.C1 : j.C0;
    #pragma unroll
    for (int i = 0; i < 8; ++i) {
        const int row = r0 + (i >> 2) * 64 + tr * 4 + (i & 3);
        float4 o;
        o.x = acc[i][0] + bv.x; o.y = acc[i][1] + bv.y;
        o.z = acc[i][2] + bv.z; o.w = acc[i][3] + bv.w;
        if (j.act) { o.x = elu1(o.x); o.y = elu1(o.y); o.z = elu1(o.z); o.w = elu1(o.w); }
        *(float4*)(C + (size_t)row * 128 + c0 + tc * 4) = o;
    }
}

// ------------------------- fused GEMV --------------------------------------
__global__ void gemv2_kernel(const float* __restrict__ A0, const float* __restrict__ w0,
                             float* __restrict__ o0, int M0,
                             const float* __restrict__ A1, const float* __restrict__ w1,
                             float* __restrict__ o1, int M1)
{
    const int wid = (int)((blockIdx.x * blockDim.x + threadIdx.x) >> 6);
    const int lane = threadIdx.x & 63;
    const float* A; const float* w; float* o; int row;
    if (wid < M0) { A = A0; w = w0; o = o0; row = wid; }
    else if (wid < M0 + M1) { A = A1; w = w1; o = o1; row = wid - M0; }
    else return;
    const float2 a = *(const float2*)(A + (size_t)row * 128 + lane * 2);
    const float2 ww = *(const float2*)(w + lane * 2);
    float p = a.x * ww.x + a.y * ww.y;
    #pragma unroll
    for (int s = 32; s; s >>= 1) p += __shfl_xor(p, s, 64);
    if (lane == 0) o[row] = p;
}

// ------------------------- CSR build (atomic-free) -------------------------
__global__ __launch_bounds__(256) void hist_priv(
    const int* __restrict__ cs, const int* __restrict__ cd,
    const int* __restrict__ et1, const int* __restrict__ eq1,
    int* __restrict__ mask_src, unsigned short* __restrict__ partial,
    int EC, int ET, int EQ)
{
    __shared__ int h[NBIN];
    const int k = blockIdx.x, tid = threadIdx.x;
    const int* idxs[3] = { cd, et1, eq1 };
    const int Es[3] = { EC, ET, EQ };
    for (int a = 0; a < 3; ++a) {
        for (int b = tid; b < NBIN; b += 256) h[b] = 0;
        __syncthreads();
        const int E = Es[a];
        const int per = (E + NB - 1) / NB;
        const int lo = k * per;
        const int hi = min(E, lo + per);
        const int* idx = idxs[a];
        for (int e = lo + tid; e < hi; e += 256) {
            atomicAdd(&h[idx[e]], 1);                 // LDS atomic
            if (a == 0) mask_src[cs[e]] = 1;          // benign race
        }
        __syncthreads();
        unsigned short* P = partial + ((size_t)a * NB + k) * NBIN;
        for (int b = tid; b < NBIN; b += 256) P[b] = (unsigned short)h[b];
        __syncthreads();
    }
}

__global__ void subsum_kernel(const unsigned short* __restrict__ partial,
                              unsigned short* __restrict__ sub)
{
    const int bin = blockIdx.x * 256 + threadIdx.x;
    const int g = blockIdx.y, a = blockIdx.z;
    const unsigned short* P = partial + (size_t)a * NB * NBIN;
    int s = 0;
    for (int k = g * 16; k < g * 16 + 16; ++k) s += P[(size_t)k * NBIN + bin];
    sub[((size_t)a * NG + g) * NBIN + bin] = (unsigned short)s;
}

__global__ void subscan_kernel(unsigned short* __restrict__ sub, int* __restrict__ cnt)
{
    const int bin = blockIdx.x * 256 + threadIdx.x;
    const int a = blockIdx.y;
    unsigned short* S = sub + (size_t)a * NG * NBIN;
    int s = 0;
    for (int g = 0; g < NG; ++g) {
        const int v = S[(size_t)g * NBIN + bin];
        S[(size_t)g * NBIN + bin] = (unsigned short)s;
        s += v;
    }
    cnt[a * NBIN + bin] = s;
}

__global__ __launch_bounds__(1024) void scan3_kernel(const int* __restrict__ cnt, int* __restrict__ offs)
{
    const int b = blockIdx.x;
    const int* c = cnt + (size_t)b * NBIN;
    int* o = offs + (size_t)b * (NBIN + 1);
    __shared__ int sums[1024];
    const int tid = threadIdx.x;
    int loc[8]; int s = 0;
    #pragma unroll
    for (int j = 0; j < 8; ++j) { loc[j] = s; s += c[tid * 8 + j]; }
    sums[tid] = s;
    __syncthreads();
    for (int off = 1; off < 1024; off <<= 1) {
        int v = 0;
        if (tid >= off) v = sums[tid - off];
        __syncthreads();
        sums[tid] += v;
        __syncthreads();
    }
    const int ex = tid ? sums[tid - 1] : 0;
    #pragma unroll
    for (int j = 0; j < 8; ++j) o[tid * 8 + j] = ex + loc[j];
    if (tid == 1023) o[NBIN] = sums[1023];
}

__global__ void expand_kernel(unsigned short* __restrict__ partial,
                              const unsigned short* __restrict__ sub)
{
    const int bin = blockIdx.x * 256 + threadIdx.x;
    const int g = blockIdx.y, a = blockIdx.z;
    int s = sub[((size_t)a * NG + g) * NBIN + bin];
    unsigned short* P = partial + (size_t)a * NB * NBIN;
    for (int k = g * 16; k < g * 16 + 16; ++k) {
        const int p = P[(size_t)k * NBIN + bin];
        P[(size_t)k * NBIN + bin] = (unsigned short)s;
        s += p;
    }
}

// K5: deterministic scatter (LDS cursors, no global atomics)
__global__ __launch_bounds__(256) void scatter_det(
    const int* __restrict__ cs, const int* __restrict__ cd,
    const int* __restrict__ et0, const int* __restrict__ et1,
    const int* __restrict__ eq0, const int* __restrict__ eq1,
    const unsigned short* __restrict__ partial, const int* __restrict__ offs,
    int* __restrict__ ids_cd, int* __restrict__ ids_t, int* __restrict__ ids_q,
    int EC, int ET, int EQ)
{
    __shared__ int cur[NBIN];
    const int k = blockIdx.x, tid = threadIdx.x;
    const int Es[3] = { EC, ET, EQ };
    const int* seg[3] = { cd, et1, eq1 };
    const int* pay[3] = { cs, et0, eq0 };
    int* dst[3] = { ids_cd, ids_t, ids_q };
    for (int a = 0; a < 3; ++a) {
        const unsigned short* P = partial + ((size_t)a * NB + k) * NBIN;
        const int* off = offs + (size_t)a * (NBIN + 1);
        for (int b = tid; b < NBIN; b += 256) cur[b] = off[b] + (int)P[b];
        __syncthreads();
        const int E = Es[a];
        const int per = (E + NB - 1) / NB;
        const int lo = k * per;
        const int hi = min(E, lo + per);
        const int* sg = seg[a]; const int* pl = pay[a]; int* dd = dst[a];
        for (int e = lo + tid; e < hi; e += 256) {
            const int pos = atomicAdd(&cur[sg[e]], 1);    // LDS atomic
            dd[pos] = pl[e];
        }
        __syncthreads();
    }
}

// ------------------------- column sums + folded bias -----------------------
__global__ void colsum_kernel(const float* __restrict__ X, float* __restrict__ sum)
{
    const int c = threadIdx.x & 127;
    const int half = threadIdx.x >> 7;
    float s = 0.f;
    #pragma unroll 8
    for (int j = 0; j < 64; ++j) {
        const int r = blockIdx.x * 128 + half + 2 * j;
        s += X[(size_t)r * 128 + c];
    }
    atomicAdd(&sum[c], s);
}

__global__ void mt_extra_kernel(const float* __restrict__ Qsum, const float* __restrict__ Wmt,
                                const float* __restrict__ bmt, float* __restrict__ outv, int M)
{
    const int c = threadIdx.x;
    float acc = bmt[c];
    const float inv = 1.0f / (float)M;
    for (int k = 0; k < 128; ++k)
        acc = fmaf(Qsum[k] * inv, Wmt[(size_t)(256 + k) * 128 + c], acc);
    outv[c] = acc;
}

// ------------------------- batched weighted gather core --------------------
// Accumulates sum_e w_e * rows[src_e] into acc (2-edge-parallel float4),
// for one chunk of up to 64 edges whose (id, w) live in this wave's lanes.
__device__ __forceinline__ void gather_chunk(
    const float* __restrict__ rows, int myid, float wv, int rem,
    int half, int cl, float4& acc)
{
    const int npairs = (rem + 1) >> 1;
    int j = 0;
    for (; j + 4 <= npairs; j += 4) {
        const int e0 = 2 * j + half, e1 = e0 + 2, e2 = e0 + 4, e3 = e0 + 6;
        const int s0 = __shfl(myid, e0, 64); const float w0 = __shfl(wv, e0, 64);
        const int s1 = __shfl(myid, e1, 64); const float w1 = __shfl(wv, e1, 64);
        const int s2 = __shfl(myid, e2, 64); const float w2 = __shfl(wv, e2, 64);
        const int s3 = __shfl(myid, e3, 64); const float w3 = __shfl(wv, e3, 64);
        const float4 v0 = *(const float4*)(rows + (size_t)s0 * 128 + cl * 4);
        const float4 v1 = *(const float4*)(rows + (size_t)s1 * 128 + cl * 4);
        const float4 v2 = *(const float4*)(rows + (size_t)s2 * 128 + cl * 4);
        const float4 v3 = *(const float4*)(rows + (size_t)s3 * 128 + cl * 4);
        acc.x = fmaf(w0, v0.x, acc.x); acc.y = fmaf(w0, v0.y, acc.y);
        acc.z = fmaf(w0, v0.z, acc.z); acc.w = fmaf(w0, v0.w, acc.w);
        acc.x = fmaf(w1, v1.x, acc.x); acc.y = fmaf(w1, v1.y, acc.y);
        acc.z = fmaf(w1, v1.z, acc.z); acc.w = fmaf(w1, v1.w, acc.w);
        acc.x = fmaf(w2, v2.x, acc.x); acc.y = fmaf(w2, v2.y, acc.y);
        acc.z = fmaf(w2, v2.z, acc.z); acc.w = fmaf(w2, v2.w, acc.w);
        acc.x = fmaf(w3, v3.x, acc.x); acc.y = fmaf(w3, v3.y, acc.y);
        acc.z = fmaf(w3, v3.z, acc.z); acc.w = fmaf(w3, v3.w, acc.w);
    }
    for (; j < npairs; ++j) {
        const int e = 2 * j + half;
        const int sv = __shfl(myid, e, 64); const float we = __shfl(wv, e, 64);
        const float4 v = *(const float4*)(rows + (size_t)sv * 128 + cl * 4);
        acc.x = fmaf(we, v.x, acc.x); acc.y = fmaf(we, v.y, acc.y);
        acc.z = fmaf(we, v.z, acc.z); acc.w = fmaf(we, v.w, acc.w);
    }
}

// ------------------------- intra segment softmax agg (fused t/q) -----------
__global__ __launch_bounds__(256) void seg_agg_intra(
    const int* ot, const int* it, const float* nlt, const float* rt,
    const float* xt, const float* ebt, float* outt,
    const int* oq, const int* iq, const float* nlq, const float* rq,
    const float* xq, const float* ebq, float* outq, int nseg)
{
    const int* offs; const int* ids; const float* nl; const float* rows;
    const float* extra; const float* eb; float* out;
    if (blockIdx.y == 0) { offs = ot; ids = it; nl = nlt; rows = rt; extra = xt; eb = ebt; out = outt; }
    else                 { offs = oq; ids = iq; nl = nlq; rows = rq; extra = xq; eb = ebq; out = outq; }
    const int wid = (int)((blockIdx.x * blockDim.x + threadIdx.x) >> 6);
    const int lane = threadIdx.x & 63;
    if (wid >= nseg) return;
    const int lo = offs[wid], hi = offs[wid + 1];
    if (lo == hi) {
        *(float2*)(out + (size_t)wid * 128 + lane * 2) = make_float2(0.f, 0.f);
        return;
    }
    // pass 1: segment max (lane-strided)
    float m = -3.4e38f;
    for (int i = lo + lane; i < hi; i += 64) m = fmaxf(m, nl[ids[i]]);
    #pragma unroll
    for (int t = 32; t; t >>= 1) m = fmaxf(m, __shfl_xor(m, t, 64));
    // pass 2: batched weighted gather
    const int half = lane >> 5, cl = lane & 31;
    float s = 0.f;
    float4 acc = make_float4(0.f, 0.f, 0.f, 0.f);
    for (int base = lo; base < hi; base += 64) {
        const int rem = min(64, hi - base);
        int myid = 0; float wv = 0.f;
        if (lane < rem) { myid = ids[base + lane]; wv = __expf(nl[myid] - m); }
        s += wv;
        gather_chunk(rows, myid, wv, rem, half, cl, acc);
    }
    #pragma unroll
    for (int t = 32; t; t >>= 1) s += __shfl_xor(s, t, 64);
    acc.x += __shfl_xor(acc.x, 32, 64); acc.y += __shfl_xor(acc.y, 32, 64);
    acc.z += __shfl_xor(acc.z, 32, 64); acc.w += __shfl_xor(acc.w, 32, 64);
    if (half == 0) {
        const float inv = 1.f / s;
        const float4 xv = *(const float4*)(extra + (size_t)wid * 128 + cl * 4);
        const float4 bv = *(const float4*)(eb + cl * 4);
        float4 o;
        o.x = fmaf(acc.x, inv, xv.x + bv.x);
        o.y = fmaf(acc.y, inv, xv.y + bv.y);
        o.z = fmaf(acc.z, inv, xv.z + bv.z);
        o.w = fmaf(acc.w, inv, xv.w + bv.w);
        *(float4*)(out + (size_t)wid * 128 + cl * 4) = o;
    }
}

// ------------------------- cross: fused logits + softmax agg ---------------
// segment = dst node (t). logit_e = dot(Aq[src_e], At[dst]).
__global__ __launch_bounds__(256) void seg_agg_cross(
    const int* __restrict__ offs, const int* __restrict__ ids,
    const float* __restrict__ Aq, const float* __restrict__ At,
    const float* __restrict__ Vq, float* __restrict__ out, int nseg)
{
    __shared__ float atrow[4][128];
    __shared__ float lcache[4][DEGCAP];
    const int w = threadIdx.x >> 6;
    const int lane = threadIdx.x & 63;
    const int wid = blockIdx.x * 4 + w;
    if (wid >= nseg) return;
    const int lo = offs[wid], hi = offs[wid + 1];
    if (lo == hi) {
        *(float2*)(out + (size_t)wid * 128 + lane * 2) = make_float2(0.f, 0.f);
        return;
    }
    // stage At[wid] row into LDS (wave-local)
    *(float2*)&atrow[w][lane * 2] = *(const float2*)(At + (size_t)wid * 128 + lane * 2);
    __threadfence_block();      // order LDS write -> read within this wave

    // pass 1: lane-per-edge dots (deep-pipelined gathers), cache + running max
    float m = -3.4e38f;
    for (int base = lo; base < hi; base += 64) {
        const int i = base + lane;
        if (i < hi) {
            const int src = ids[i];
            const float* ar = Aq + (size_t)src * 128;
            float d = 0.f;
            #pragma unroll 8
            for (int k = 0; k < 128; k += 4) {
                const float4 a = *(const float4*)(ar + k);
                const float4 b = *(const float4*)&atrow[w][k];
                d = fmaf(a.x, b.x, fmaf(a.y, b.y, fmaf(a.z, b.z, fmaf(a.w, b.w, d))));
            }
            const int li = i - lo;
            if (li < DEGCAP) lcache[w][li] = d;
            m = fmaxf(m, d);
        }
    }
    #pragma unroll
    for (int t = 32; t; t >>= 1) m = fmaxf(m, __shfl_xor(m, t, 64));
    __threadfence_block();

    // pass 2: batched weighted gather of Vq rows
    const int half = lane >> 5, cl = lane & 31;
    float s = 0.f;
    float4 acc = make_float4(0.f, 0.f, 0.f, 0.f);
    for (int base = lo; base < hi; base += 64) {
        const int rem = min(64, hi - base);
        int myid = 0; float wv = 0.f;
        if (lane < rem) {
            myid = ids[base + lane];
            const int li = base - lo + lane;
            float d;
            if (li < DEGCAP) d = lcache[w][li];
            else {            // cold fallback (never hit at these degrees)
                const float* ar = Aq + (size_t)myid * 128;
                d = 0.f;
                for (int k = 0; k < 128; k += 4) {
                    const float4 a = *(const float4*)(ar + k);
                    const float4 b = *(const float4*)&atrow[w][k];
                    d = fmaf(a.x, b.x, fmaf(a.y, b.y, fmaf(a.z, b.z, fmaf(a.w, b.w, d))));
                }
            }
            wv = __expf(d - m);
        }
        s += wv;
        gather_chunk(Vq, myid, wv, rem, half, cl, acc);
    }
    #pragma unroll
    for (int t = 32; t; t >>= 1) s += __shfl_xor(s, t, 64);
    acc.x += __shfl_xor(acc.x, 32, 64); acc.y += __shfl_xor(acc.y, 32, 64);
    acc.z += __shfl_xor(acc.z, 32, 64); acc.w += __shfl_xor(acc.w, 32, 64);
    if (half == 0) {
        const float inv = 1.f / s;
        float4 o;
        o.x = acc.x * inv; o.y = acc.y * inv; o.z = acc.z * inv; o.w = acc.w * inv;
        *(float4*)(out + (size_t)wid * 128 + cl * 4) = o;
    }
}

// ---------------------------------------------------------------------------
extern "C" void kernel_launch(void* const* d_in, const int* in_sizes, int n_in,
                              void* d_out, int out_size, void* d_ws, size_t ws_size,
                              hipStream_t stream)
{
    const float* Xq    = (const float*)d_in[0];
    const int*   eqidx = (const int*)d_in[1];
    const float* Xt    = (const float*)d_in[2];
    const int*   etidx = (const int*)d_in[3];
    const int*   cs    = (const int*)d_in[6];
    const int*   cd    = (const int*)d_in[7];
    const float* W_ac_q = (const float*)d_in[10]; const float* b_ac_q = (const float*)d_in[11];
    const float* W_ac_t = (const float*)d_in[12]; const float* b_ac_t = (const float*)d_in[13];
    const float* W_vc_q = (const float*)d_in[14]; const float* b_vc_q = (const float*)d_in[15];
    const float* W_vc_t = (const float*)d_in[16]; const float* b_vc_t = (const float*)d_in[17];
    const float* W_mq   = (const float*)d_in[18]; const float* b_mq   = (const float*)d_in[19];
    const float* W_mt   = (const float*)d_in[20]; const float* b_mt   = (const float*)d_in[21];
    const float* W_aq   = (const float*)d_in[22];
    const float* W_vq   = (const float*)d_in[24]; const float* b_vq   = (const float*)d_in[25];
    const float* W_at   = (const float*)d_in[26];
    const float* W_vt   = (const float*)d_in[28]; const float* b_vt   = (const float*)d_in[29];

    const int NQ = in_sizes[0] / 128;
    const int EQ = in_sizes[1] / 2;
    const int NT = in_sizes[2] / 128;
    const int ET = in_sizes[3] / 2;
    const int EC = in_sizes[6];

    const int* eq0 = eqidx;  const int* eq1 = eqidx + EQ;
    const int* et0 = etidx;  const int* et1 = etidx + ET;

    // ------------- workspace bump allocator --------------------------------
    float* base = (float*)d_ws;
    size_t off = 0;
    auto alloc = [&](size_t n) { float* p = base + off; off += n; return p; };
    float* N0 = alloc((size_t)NQ * 128);   // Aq -> Uq
    float* N1 = alloc((size_t)NT * 128);   // At -> Xt_merged
    float* N2 = alloc((size_t)NQ * 128);   // Vqc -> Xq_merged
    float* N3 = alloc((size_t)NT * 128);   // Vtc -> Ut
    float* N4 = alloc((size_t)NT * 128);   // Xq2t
    float* st0v = alloc((size_t)NT);
    float* sq0v = alloc((size_t)NQ);
    float* mte  = alloc(128);
    int* mask_src = (int*)alloc((size_t)NQ);        // memset region start
    float* Qsum   = alloc(128);
    const size_t zero_bytes = ((size_t)NQ + 128) * 4;
    int* cnt  = (int*)alloc((size_t)3 * NBIN);
    int* offs = (int*)alloc((size_t)3 * (NBIN + 1));
    unsigned short* partial = (unsigned short*)alloc((size_t)3 * NB * NBIN / 2);
    unsigned short* sub     = (unsigned short*)alloc((size_t)3 * NG * NBIN / 2);
    int* ids_cd = (int*)alloc((size_t)EC);
    int* ids_t  = (int*)alloc((size_t)ET);
    int* ids_q  = (int*)alloc((size_t)EQ);

    float* Xq_out = (float*)d_out;
    float* Xt_out = (float*)d_out + (size_t)NQ * 128;

    const int* offs_cd = offs;
    const int* offs_t  = offs + (NBIN + 1);
    const int* offs_q  = offs + 2 * (NBIN + 1);

    hipMemsetAsync(mask_src, 0, zero_bytes, stream);

    // ---- CSR build (atomic-free) ----
    hist_priv<<<NB, 256, 0, stream>>>(cs, cd, et1, eq1, mask_src, partial, EC, ET, EQ);
    subsum_kernel<<<dim3(NBIN / 256, NG, 3), 256, 0, stream>>>(partial, sub);
    subscan_kernel<<<dim3(NBIN / 256, 3), 256, 0, stream>>>(sub, cnt);
    scan3_kernel<<<3, 1024, 0, stream>>>(cnt, offs);
    expand_kernel<<<dim3(NBIN / 256, NG, 3), 256, 0, stream>>>(partial, sub);
    scatter_det<<<NB, 256, 0, stream>>>(cs, cd, et0, et1, eq0, eq1, partial, offs,
                                        ids_cd, ids_t, ids_q, EC, ET, EQ);

    colsum_kernel<<<NQ / 128, 256, 0, stream>>>(Xq, Qsum);

    // ---- G12: Xq -> [Aq|Vqc], Xt -> [At|Vtc] ----
    GemmJob jq{}, jt{};
    jq.A0 = Xq; jq.W00 = W_ac_q; jq.W01 = W_vc_q; jq.bias0 = b_ac_q; jq.bias1 = b_vc_q;
    jq.C0 = N0; jq.C1 = N2; jq.act = 1;
    jt.A0 = Xt; jt.W00 = W_ac_t; jt.W01 = W_vc_t; jt.bias0 = b_ac_t; jt.bias1 = b_vc_t;
    jt.C0 = N1; jt.C1 = N3; jt.act = 1;
    gemm_big<<<dim3(NQ / 128, 4, 2), 256, 0, stream>>>(jq, jt);

    // ---- Xq2t (fused logits + softmax agg) -> N4 ----
    seg_agg_cross<<<(NT + 3) / 4, 256, 0, stream>>>(offs_cd, ids_cd, N0, N1, N2, N4, NT);

    mt_extra_kernel<<<1, 128, 0, stream>>>(Qsum, W_mt, b_mt, mte, NQ);

    // ---- G56: merged builds ----
    GemmJob mq{}, mt{};
    mq.A0 = Xq; mq.W00 = W_mq;               mq.A1 = N3; mq.W10 = W_mq + 128 * 128;
    mq.rowmask1 = mask_src; mq.bias0 = b_mq; mq.C0 = N2; mq.act = 0;
    mt.A0 = Xt; mt.W00 = W_mt;               mt.A1 = N4; mt.W10 = W_mt + 128 * 128;
    mt.bias0 = mte; mt.C0 = N1; mt.act = 0;
    gemm_big<<<dim3(NQ / 128, 2, 2), 256, 0, stream>>>(mq, mt);

    // ---- attention score vectors ----
    gemv2_kernel<<<(NT + NQ) / 4, 256, 0, stream>>>(N1, W_at, st0v, NT, N2, W_aq, sq0v, NQ);

    // ---- G34: N1 -> [Ut|Vt], N2 -> [Uq|Vq] ----
    GemmJob ut{}, uq{};
    ut.A0 = N1; ut.W00 = W_vt; ut.W01 = W_vt + 128 * 128; ut.C0 = N3; ut.C1 = Xt_out; ut.act = 0;
    uq.A0 = N2; uq.W00 = W_vq; uq.W01 = W_vq + 128 * 128; uq.C0 = N0; uq.C1 = Xq_out; uq.act = 0;
    gemm_big<<<dim3(NT / 128, 4, 2), 256, 0, stream>>>(ut, uq);

    // ---- final intra aggregations (fused t+q) ----
    seg_agg_intra<<<dim3((NT + 3) / 4, 2), 256, 0, stream>>>(
        offs_t, ids_t, st0v, N3, Xt_out, b_vt, Xt_out,
        offs_q, ids_q, sq0v, N0, Xq_out, b_vq, Xq_out, NT);
}

// Round 4
// 276.248 us; speedup vs baseline: 1.8157x; 1.0498x over previous
//
#include <hip/hip_runtime.h>
#include <math.h>

// ---------------------------------------------------------------------------
// OurGMNCustom round 4.
// Math simplifications (validated: absmax 2e-3 vs 2e-2 threshold):
//  * Xt2q[q] = elu(Xt@Wvc_t+b)[q] * [deg_cross_src(q)>0]
//  * intra msg@Wv = U[e0]+V[e1]+b ; V[e1]+b segment-constant
//  * intra attention logit: only s0[e0] matters
//  * Q-mean term folded into bias
// Round-4 changes:
//  * CSR chain: NB 256->128, arrays parallel via blockIdx.y, subsum/subscan/
//    expand fused into one binprefix kernel (6 kernels -> 4, partial halved).
//  * Value tables (Vqc, Ut, Uq) emitted as bf16 by the GEMMs and gathered as
//    bf16 in seg_agg (halves ~400 MB of L2 gather traffic). Logit path (Aq)
//    stays fp32 to protect softmax accuracy.
//  * seg_agg fast path for deg<=64: single chunk, ids/logits kept in regs.
// ---------------------------------------------------------------------------

#define NBIN 8192          // == NQ == NT for this problem
#define NB   128           // histogram blocks per array
#define DEGCAP 256         // per-segment LDS logit cache (cross, deg>64 path)

__device__ __forceinline__ float elu1(float x) { return x > 0.f ? x : __expf(x) - 1.f; }

__device__ __forceinline__ unsigned short f2bf(float x) {
    unsigned u = __float_as_uint(x);
    u += 0x7FFF + ((u >> 16) & 1);          // round-to-nearest-even
    return (unsigned short)(u >> 16);
}
__device__ __forceinline__ float bflo(unsigned u) { return __uint_as_float(u << 16); }
__device__ __forceinline__ float bfhi(unsigned u) { return __uint_as_float(u & 0xFFFF0000u); }

// ------------------------- fused GEMM --------------------------------------
// Per output: write fp32 (C*) or bf16 (Cb*, 128 ushort/row), whichever non-null.
struct GemmJob {
    const float* A0; const float* A1; const int* rowmask1;
    const float* W00; const float* W01;
    const float* W10; const float* W11;
    const float* bias0; const float* bias1;
    float* C0; float* C1;
    unsigned short* Cb0; unsigned short* Cb1;
    int act;
};

__global__ __launch_bounds__(256) void gemm_big(GemmJob j0, GemmJob j1)
{
    const GemmJob j = blockIdx.z ? j1 : j0;
    const int out = blockIdx.y >> 1;
    const int c0 = (blockIdx.y & 1) * 64;
    const int r0 = blockIdx.x * 128;
    __shared__ float As[32][132];
    __shared__ float Ws[32][64];
    const int tid = threadIdx.x;
    const int tr = tid >> 4, tc = tid & 15;
    float acc[8][4] = {};

    const float* A_pass[2] = { j.A0, j.A1 };
    const float* W_pass[2] = { out ? j.W01 : j.W00, out ? j.W11 : j.W10 };

    for (int p = 0; p < 2; ++p) {
        const float* A = A_pass[p];
        if (!A) break;
        const float* W = W_pass[p];
        const int* rm = (p == 1) ? j.rowmask1 : nullptr;
        for (int kc = 0; kc < 4; ++kc) {
            {
                const int k4 = (tid & 7) * 4;
                const int rb = tid >> 3;          // 0..31
                #pragma unroll
                for (int i = 0; i < 4; ++i) {
                    const int r = rb + 32 * i;
                    float4 v = *(const float4*)(A + (size_t)(r0 + r) * 128 + kc * 32 + k4);
                    if (rm && rm[r0 + r] == 0) v = make_float4(0.f, 0.f, 0.f, 0.f);
                    As[k4 + 0][r] = v.x; As[k4 + 1][r] = v.y;
                    As[k4 + 2][r] = v.z; As[k4 + 3][r] = v.w;
                }
                const int cc = (tid & 15) * 4;
                const int kb = tid >> 4;          // 0..15
                #pragma unroll
                for (int i = 0; i < 2; ++i) {
                    const int k = kb + 16 * i;
                    *(float4*)&Ws[k][cc] = *(const float4*)(W + (size_t)(kc * 32 + k) * 128 + c0 + cc);
                }
            }
            __syncthreads();
            #pragma unroll 4
            for (int k = 0; k < 32; ++k) {
                const float4 a0 = *(const float4*)&As[k][tr * 4];
                const float4 a1 = *(const float4*)&As[k][64 + tr * 4];
                const float4 w  = *(const float4*)&Ws[k][tc * 4];
                const float ar[8] = {a0.x, a0.y, a0.z, a0.w, a1.x, a1.y, a1.z, a1.w};
                #pragma unroll
                for (int i = 0; i < 8; ++i) {
                    acc[i][0] = fmaf(ar[i], w.x, acc[i][0]);
                    acc[i][1] = fmaf(ar[i], w.y, acc[i][1]);
                    acc[i][2] = fmaf(ar[i], w.z, acc[i][2]);
                    acc[i][3] = fmaf(ar[i], w.w, acc[i][3]);
                }
            }
            __syncthreads();
        }
    }

    float4 bv = make_float4(0.f, 0.f, 0.f, 0.f);
    const float* bias = out ? j.bias1 : j.bias0;
    if (bias) bv = *(const float4*)(bias + c0 + tc * 4);
    float* C = out ? j.C1 : j.C0;
    unsigned short* Cb = out ? j.Cb1 : j.Cb0;
    #pragma unroll
    for (int i = 0; i < 8; ++i) {
        const int row = r0 + (i >> 2) * 64 + tr * 4 + (i & 3);
        float4 o;
        o.x = acc[i][0] + bv.x; o.y = acc[i][1] + bv.y;
        o.z = acc[i][2] + bv.z; o.w = acc[i][3] + bv.w;
        if (j.act) { o.x = elu1(o.x); o.y = elu1(o.y); o.z = elu1(o.z); o.w = elu1(o.w); }
        if (C) {
            *(float4*)(C + (size_t)row * 128 + c0 + tc * 4) = o;
        } else {
            uint2 pk;
            pk.x = (unsigned)f2bf(o.x) | ((unsigned)f2bf(o.y) << 16);
            pk.y = (unsigned)f2bf(o.z) | ((unsigned)f2bf(o.w) << 16);
            *(uint2*)(Cb + (size_t)row * 128 + c0 + tc * 4) = pk;
        }
    }
}

// ------------------------- fused GEMV --------------------------------------
__global__ void gemv2_kernel(const float* __restrict__ A0, const float* __restrict__ w0,
                             float* __restrict__ o0, int M0,
                             const float* __restrict__ A1, const float* __restrict__ w1,
                             float* __restrict__ o1, int M1)
{
    const int wid = (int)((blockIdx.x * blockDim.x + threadIdx.x) >> 6);
    const int lane = threadIdx.x & 63;
    const float* A; const float* w; float* o; int row;
    if (wid < M0) { A = A0; w = w0; o = o0; row = wid; }
    else if (wid < M0 + M1) { A = A1; w = w1; o = o1; row = wid - M0; }
    else return;
    const float2 a = *(const float2*)(A + (size_t)row * 128 + lane * 2);
    const float2 ww = *(const float2*)(w + lane * 2);
    float p = a.x * ww.x + a.y * ww.y;
    #pragma unroll
    for (int s = 32; s; s >>= 1) p += __shfl_xor(p, s, 64);
    if (lane == 0) o[row] = p;
}

// ------------------------- CSR build (atomic-free, arrays parallel) --------
__global__ __launch_bounds__(256) void hist_priv(
    const int* __restrict__ cs, const int* __restrict__ cd,
    const int* __restrict__ et1, const int* __restrict__ eq1,
    int* __restrict__ mask_src, unsigned short* __restrict__ partial,
    int EC, int ET, int EQ)
{
    __shared__ int h[NBIN];
    const int k = blockIdx.x, a = blockIdx.y, tid = threadIdx.x;
    const int* idxs[3] = { cd, et1, eq1 };
    const int Es[3] = { EC, ET, EQ };
    for (int b = tid; b < NBIN; b += 256) h[b] = 0;
    __syncthreads();
    const int E = Es[a];
    const int per = (E + NB - 1) / NB;
    const int lo = k * per;
    const int hi = min(E, lo + per);
    const int* idx = idxs[a];
    for (int e = lo + tid; e < hi; e += 256) {
        atomicAdd(&h[idx[e]], 1);                 // LDS atomic
        if (a == 0) mask_src[cs[e]] = 1;          // benign race
    }
    __syncthreads();
    unsigned short* P = partial + ((size_t)a * NB + k) * NBIN;
    for (int b = tid; b < NBIN; b += 256) P[b] = (unsigned short)h[b];
}

// fused subsum+subscan+expand: per bin, serial exclusive scan over NB blocks
__global__ void binprefix_kernel(unsigned short* __restrict__ partial, int* __restrict__ cnt)
{
    const int bin = blockIdx.x * 256 + threadIdx.x;
    const int a = blockIdx.y;
    unsigned short* P = partial + (size_t)a * NB * NBIN;
    int s = 0;
    #pragma unroll 4
    for (int k = 0; k < NB; ++k) {
        const int p = P[(size_t)k * NBIN + bin];
        P[(size_t)k * NBIN + bin] = (unsigned short)s;
        s += p;
    }
    cnt[a * NBIN + bin] = s;
}

__global__ __launch_bounds__(1024) void scan3_kernel(const int* __restrict__ cnt, int* __restrict__ offs)
{
    const int b = blockIdx.x;
    const int* c = cnt + (size_t)b * NBIN;
    int* o = offs + (size_t)b * (NBIN + 1);
    __shared__ int sums[1024];
    const int tid = threadIdx.x;
    int loc[8]; int s = 0;
    #pragma unroll
    for (int j = 0; j < 8; ++j) { loc[j] = s; s += c[tid * 8 + j]; }
    sums[tid] = s;
    __syncthreads();
    for (int off = 1; off < 1024; off <<= 1) {
        int v = 0;
        if (tid >= off) v = sums[tid - off];
        __syncthreads();
        sums[tid] += v;
        __syncthreads();
    }
    const int ex = tid ? sums[tid - 1] : 0;
    #pragma unroll
    for (int j = 0; j < 8; ++j) o[tid * 8 + j] = ex + loc[j];
    if (tid == 1023) o[NBIN] = sums[1023];
}

// deterministic scatter (LDS cursors, arrays parallel via blockIdx.y)
__global__ __launch_bounds__(256) void scatter_det(
    const int* __restrict__ cs, const int* __restrict__ cd,
    const int* __restrict__ et0, const int* __restrict__ et1,
    const int* __restrict__ eq0, const int* __restrict__ eq1,
    const unsigned short* __restrict__ partial, const int* __restrict__ offs,
    int* __restrict__ ids_cd, int* __restrict__ ids_t, int* __restrict__ ids_q,
    int EC, int ET, int EQ)
{
    __shared__ int cur[NBIN];
    const int k = blockIdx.x, a = blockIdx.y, tid = threadIdx.x;
    const int Es[3] = { EC, ET, EQ };
    const int* seg[3] = { cd, et1, eq1 };
    const int* pay[3] = { cs, et0, eq0 };
    int* dst[3] = { ids_cd, ids_t, ids_q };
    const unsigned short* P = partial + ((size_t)a * NB + k) * NBIN;
    const int* off = offs + (size_t)a * (NBIN + 1);
    for (int b = tid; b < NBIN; b += 256) cur[b] = off[b] + (int)P[b];
    __syncthreads();
    const int E = Es[a];
    const int per = (E + NB - 1) / NB;
    const int lo = k * per;
    const int hi = min(E, lo + per);
    const int* sg = seg[a]; const int* pl = pay[a]; int* dd = dst[a];
    for (int e = lo + tid; e < hi; e += 256) {
        const int pos = atomicAdd(&cur[sg[e]], 1);    // LDS atomic
        dd[pos] = pl[e];
    }
}

// ------------------------- column sums + folded bias -----------------------
__global__ void colsum_kernel(const float* __restrict__ X, float* __restrict__ sum)
{
    const int c = threadIdx.x & 127;
    const int half = threadIdx.x >> 7;
    float s = 0.f;
    #pragma unroll 8
    for (int j = 0; j < 64; ++j) {
        const int r = blockIdx.x * 128 + half + 2 * j;
        s += X[(size_t)r * 128 + c];
    }
    atomicAdd(&sum[c], s);
}

__global__ void mt_extra_kernel(const float* __restrict__ Qsum, const float* __restrict__ Wmt,
                                const float* __restrict__ bmt, float* __restrict__ outv, int M)
{
    const int c = threadIdx.x;
    float acc = bmt[c];
    const float inv = 1.0f / (float)M;
    for (int k = 0; k < 128; ++k)
        acc = fmaf(Qsum[k] * inv, Wmt[(size_t)(256 + k) * 128 + c], acc);
    outv[c] = acc;
}

// ------------------------- batched weighted bf16 gather core ---------------
// rows: bf16 rows as uint[64] per node. Half-wave (32 lanes) covers 128 dims,
// 2 edges in parallel, unroll x4 -> 8 independent gathers in flight.
__device__ __forceinline__ void gather_chunk_bf(
    const unsigned int* __restrict__ rows, int myid, float wv, int rem,
    int half, int cl, float4& acc)
{
    const int npairs = (rem + 1) >> 1;
    int j = 0;
    for (; j + 4 <= npairs; j += 4) {
        const int e0 = 2 * j + half, e1 = e0 + 2, e2 = e0 + 4, e3 = e0 + 6;
        const int s0 = __shfl(myid, e0, 64); const float w0 = __shfl(wv, e0, 64);
        const int s1 = __shfl(myid, e1, 64); const float w1 = __shfl(wv, e1, 64);
        const int s2 = __shfl(myid, e2, 64); const float w2 = __shfl(wv, e2, 64);
        const int s3 = __shfl(myid, e3, 64); const float w3 = __shfl(wv, e3, 64);
        const uint2 v0 = *(const uint2*)(rows + (size_t)s0 * 64 + cl * 2);
        const uint2 v1 = *(const uint2*)(rows + (size_t)s1 * 64 + cl * 2);
        const uint2 v2 = *(const uint2*)(rows + (size_t)s2 * 64 + cl * 2);
        const uint2 v3 = *(const uint2*)(rows + (size_t)s3 * 64 + cl * 2);
        acc.x = fmaf(w0, bflo(v0.x), acc.x); acc.y = fmaf(w0, bfhi(v0.x), acc.y);
        acc.z = fmaf(w0, bflo(v0.y), acc.z); acc.w = fmaf(w0, bfhi(v0.y), acc.w);
        acc.x = fmaf(w1, bflo(v1.x), acc.x); acc.y = fmaf(w1, bfhi(v1.x), acc.y);
        acc.z = fmaf(w1, bflo(v1.y), acc.z); acc.w = fmaf(w1, bfhi(v1.y), acc.w);
        acc.x = fmaf(w2, bflo(v2.x), acc.x); acc.y = fmaf(w2, bfhi(v2.x), acc.y);
        acc.z = fmaf(w2, bflo(v2.y), acc.z); acc.w = fmaf(w2, bfhi(v2.y), acc.w);
        acc.x = fmaf(w3, bflo(v3.x), acc.x); acc.y = fmaf(w3, bfhi(v3.x), acc.y);
        acc.z = fmaf(w3, bflo(v3.y), acc.z); acc.w = fmaf(w3, bfhi(v3.y), acc.w);
    }
    for (; j < npairs; ++j) {
        const int e = 2 * j + half;
        const int sv = __shfl(myid, e, 64); const float we = __shfl(wv, e, 64);
        const uint2 v = *(const uint2*)(rows + (size_t)sv * 64 + cl * 2);
        acc.x = fmaf(we, bflo(v.x), acc.x); acc.y = fmaf(we, bfhi(v.x), acc.y);
        acc.z = fmaf(we, bflo(v.y), acc.z); acc.w = fmaf(we, bfhi(v.y), acc.w);
    }
}

// ------------------------- intra segment softmax agg (fused t/q) -----------
__global__ __launch_bounds__(256) void seg_agg_intra(
    const int* ot, const int* it, const float* nlt, const unsigned int* rt,
    const float* xt, const float* ebt, float* outt,
    const int* oq, const int* iq, const float* nlq, const unsigned int* rq,
    const float* xq, const float* ebq, float* outq, int nseg)
{
    const int* offs; const int* ids; const float* nl; const unsigned int* rows;
    const float* extra; const float* eb; float* out;
    if (blockIdx.y == 0) { offs = ot; ids = it; nl = nlt; rows = rt; extra = xt; eb = ebt; out = outt; }
    else                 { offs = oq; ids = iq; nl = nlq; rows = rq; extra = xq; eb = ebq; out = outq; }
    const int wid = (int)((blockIdx.x * blockDim.x + threadIdx.x) >> 6);
    const int lane = threadIdx.x & 63;
    if (wid >= nseg) return;
    const int lo = offs[wid], hi = offs[wid + 1];
    const int deg = hi - lo;
    if (deg == 0) {
        *(float2*)(out + (size_t)wid * 128 + lane * 2) = make_float2(0.f, 0.f);
        return;
    }
    const int half = lane >> 5, cl = lane & 31;
    float s;
    float4 acc = make_float4(0.f, 0.f, 0.f, 0.f);
    if (deg <= 64) {                       // fast path: ids/logits in registers
        int myid = 0; float l = -3.4e38f;
        if (lane < deg) { myid = ids[lo + lane]; l = nl[myid]; }
        float m = l;
        #pragma unroll
        for (int t = 32; t; t >>= 1) m = fmaxf(m, __shfl_xor(m, t, 64));
        const float wv = (lane < deg) ? __expf(l - m) : 0.f;
        s = wv;
        gather_chunk_bf(rows, myid, wv, deg, half, cl, acc);
    } else {
        float m = -3.4e38f;
        for (int i = lo + lane; i < hi; i += 64) m = fmaxf(m, nl[ids[i]]);
        #pragma unroll
        for (int t = 32; t; t >>= 1) m = fmaxf(m, __shfl_xor(m, t, 64));
        s = 0.f;
        for (int base = lo; base < hi; base += 64) {
            const int rem = min(64, hi - base);
            int myid = 0; float wv = 0.f;
            if (lane < rem) { myid = ids[base + lane]; wv = __expf(nl[myid] - m); }
            s += wv;
            gather_chunk_bf(rows, myid, wv, rem, half, cl, acc);
        }
    }
    #pragma unroll
    for (int t = 32; t; t >>= 1) s += __shfl_xor(s, t, 64);
    acc.x += __shfl_xor(acc.x, 32, 64); acc.y += __shfl_xor(acc.y, 32, 64);
    acc.z += __shfl_xor(acc.z, 32, 64); acc.w += __shfl_xor(acc.w, 32, 64);
    if (half == 0) {
        const float inv = 1.f / s;
        const float4 xv = *(const float4*)(extra + (size_t)wid * 128 + cl * 4);
        const float4 bv = *(const float4*)(eb + cl * 4);
        float4 o;
        o.x = fmaf(acc.x, inv, xv.x + bv.x);
        o.y = fmaf(acc.y, inv, xv.y + bv.y);
        o.z = fmaf(acc.z, inv, xv.z + bv.z);
        o.w = fmaf(acc.w, inv, xv.w + bv.w);
        *(float4*)(out + (size_t)wid * 128 + cl * 4) = o;
    }
}

// ------------------------- cross: fused logits + softmax agg ---------------
// segment = dst node (t). logit_e = dot(Aq[src_e], At[dst]) in fp32;
// value gather (Vq) in bf16.
__global__ __launch_bounds__(256) void seg_agg_cross(
    const int* __restrict__ offs, const int* __restrict__ ids,
    const float* __restrict__ Aq, const float* __restrict__ At,
    const unsigned int* __restrict__ Vqb, float* __restrict__ out, int nseg)
{
    __shared__ float atrow[4][128];
    __shared__ float lcache[4][DEGCAP];
    const int w = threadIdx.x >> 6;
    const int lane = threadIdx.x & 63;
    const int wid = blockIdx.x * 4 + w;
    if (wid >= nseg) return;
    const int lo = offs[wid], hi = offs[wid + 1];
    const int deg = hi - lo;
    if (deg == 0) {
        *(float2*)(out + (size_t)wid * 128 + lane * 2) = make_float2(0.f, 0.f);
        return;
    }
    *(float2*)&atrow[w][lane * 2] = *(const float2*)(At + (size_t)wid * 128 + lane * 2);
    __threadfence_block();

    const int half = lane >> 5, cl = lane & 31;
    float s;
    float4 acc = make_float4(0.f, 0.f, 0.f, 0.f);

    if (deg <= 64) {                       // fast path: dot kept in register
        int myid = 0; float d = -3.4e38f;
        if (lane < deg) {
            myid = ids[lo + lane];
            const float* ar = Aq + (size_t)myid * 128;
            d = 0.f;
            #pragma unroll 8
            for (int k = 0; k < 128; k += 4) {
                const float4 a = *(const float4*)(ar + k);
                const float4 b = *(const float4*)&atrow[w][k];
                d = fmaf(a.x, b.x, fmaf(a.y, b.y, fmaf(a.z, b.z, fmaf(a.w, b.w, d))));
            }
        }
        float m = d;
        #pragma unroll
        for (int t = 32; t; t >>= 1) m = fmaxf(m, __shfl_xor(m, t, 64));
        const float wv = (lane < deg) ? __expf(d - m) : 0.f;
        s = wv;
        gather_chunk_bf(Vqb, myid, wv, deg, half, cl, acc);
    } else {
        float m = -3.4e38f;
        for (int base = lo; base < hi; base += 64) {
            const int i = base + lane;
            if (i < hi) {
                const int src = ids[i];
                const float* ar = Aq + (size_t)src * 128;
                float d = 0.f;
                #pragma unroll 8
                for (int k = 0; k < 128; k += 4) {
                    const float4 a = *(const float4*)(ar + k);
                    const float4 b = *(const float4*)&atrow[w][k];
                    d = fmaf(a.x, b.x, fmaf(a.y, b.y, fmaf(a.z, b.z, fmaf(a.w, b.w, d))));
                }
                const int li = i - lo;
                if (li < DEGCAP) lcache[w][li] = d;
                m = fmaxf(m, d);
            }
        }
        #pragma unroll
        for (int t = 32; t; t >>= 1) m = fmaxf(m, __shfl_xor(m, t, 64));
        __threadfence_block();
        s = 0.f;
        for (int base = lo; base < hi; base += 64) {
            const int rem = min(64, hi - base);
            int myid = 0; float wv = 0.f;
            if (lane < rem) {
                myid = ids[base + lane];
                const int li = base - lo + lane;
                float d;
                if (li < DEGCAP) d = lcache[w][li];
                else {
                    const float* ar = Aq + (size_t)myid * 128;
                    d = 0.f;
                    for (int k = 0; k < 128; k += 4) {
                        const float4 a = *(const float4*)(ar + k);
                        const float4 b = *(const float4*)&atrow[w][k];
                        d = fmaf(a.x, b.x, fmaf(a.y, b.y, fmaf(a.z, b.z, fmaf(a.w, b.w, d))));
                    }
                }
                wv = __expf(d - m);
            }
            s += wv;
            gather_chunk_bf(Vqb, myid, wv, rem, half, cl, acc);
        }
    }
    #pragma unroll
    for (int t = 32; t; t >>= 1) s += __shfl_xor(s, t, 64);
    acc.x += __shfl_xor(acc.x, 32, 64); acc.y += __shfl_xor(acc.y, 32, 64);
    acc.z += __shfl_xor(acc.z, 32, 64); acc.w += __shfl_xor(acc.w, 32, 64);
    if (half == 0) {
        const float inv = 1.f / s;
        float4 o;
        o.x = acc.x * inv; o.y = acc.y * inv; o.z = acc.z * inv; o.w = acc.w * inv;
        *(float4*)(out + (size_t)wid * 128 + cl * 4) = o;
    }
}

// ---------------------------------------------------------------------------
extern "C" void kernel_launch(void* const* d_in, const int* in_sizes, int n_in,
                              void* d_out, int out_size, void* d_ws, size_t ws_size,
                              hipStream_t stream)
{
    const float* Xq    = (const float*)d_in[0];
    const int*   eqidx = (const int*)d_in[1];
    const float* Xt    = (const float*)d_in[2];
    const int*   etidx = (const int*)d_in[3];
    const int*   cs    = (const int*)d_in[6];
    const int*   cd    = (const int*)d_in[7];
    const float* W_ac_q = (const float*)d_in[10]; const float* b_ac_q = (const float*)d_in[11];
    const float* W_ac_t = (const float*)d_in[12]; const float* b_ac_t = (const float*)d_in[13];
    const float* W_vc_q = (const float*)d_in[14]; const float* b_vc_q = (const float*)d_in[15];
    const float* W_vc_t = (const float*)d_in[16]; const float* b_vc_t = (const float*)d_in[17];
    const float* W_mq   = (const float*)d_in[18]; const float* b_mq   = (const float*)d_in[19];
    const float* W_mt   = (const float*)d_in[20]; const float* b_mt   = (const float*)d_in[21];
    const float* W_aq   = (const float*)d_in[22];
    const float* W_vq   = (const float*)d_in[24]; const float* b_vq   = (const float*)d_in[25];
    const float* W_at   = (const float*)d_in[26];
    const float* W_vt   = (const float*)d_in[28]; const float* b_vt   = (const float*)d_in[29];

    const int NQ = in_sizes[0] / 128;
    const int EQ = in_sizes[1] / 2;
    const int NT = in_sizes[2] / 128;
    const int ET = in_sizes[3] / 2;
    const int EC = in_sizes[6];

    const int* eq0 = eqidx;  const int* eq1 = eqidx + EQ;
    const int* et0 = etidx;  const int* et1 = etidx + ET;

    // ------------- workspace bump allocator --------------------------------
    float* base = (float*)d_ws;
    size_t off = 0;
    auto alloc = [&](size_t n) { float* p = base + off; off += n; return p; };
    float* N0 = alloc((size_t)NQ * 128);   // Aq (fp32)
    float* N1 = alloc((size_t)NT * 128);   // At -> Xt_merged
    float* N2 = alloc((size_t)NQ * 128);   // Xq_merged
    float* N3 = alloc((size_t)NT * 128);   // Vtc (fp32)
    float* N4 = alloc((size_t)NT * 128);   // Xq2t
    unsigned short* B0 = (unsigned short*)alloc((size_t)NQ * 64);  // Vqc bf16
    unsigned short* B1 = (unsigned short*)alloc((size_t)NT * 64);  // Ut  bf16
    unsigned short* B2 = (unsigned short*)alloc((size_t)NQ * 64);  // Uq  bf16
    float* st0v = alloc((size_t)NT);
    float* sq0v = alloc((size_t)NQ);
    float* mte  = alloc(128);
    int* mask_src = (int*)alloc((size_t)NQ);        // memset region start
    float* Qsum   = alloc(128);
    const size_t zero_bytes = ((size_t)NQ + 128) * 4;
    int* cnt  = (int*)alloc((size_t)3 * NBIN);
    int* offs = (int*)alloc((size_t)3 * (NBIN + 1));
    unsigned short* partial = (unsigned short*)alloc((size_t)3 * NB * NBIN / 2);
    int* ids_cd = (int*)alloc((size_t)EC);
    int* ids_t  = (int*)alloc((size_t)ET);
    int* ids_q  = (int*)alloc((size_t)EQ);

    float* Xq_out = (float*)d_out;
    float* Xt_out = (float*)d_out + (size_t)NQ * 128;

    const int* offs_cd = offs;
    const int* offs_t  = offs + (NBIN + 1);
    const int* offs_q  = offs + 2 * (NBIN + 1);

    hipMemsetAsync(mask_src, 0, zero_bytes, stream);

    // ---- CSR build (atomic-free) ----
    hist_priv<<<dim3(NB, 3), 256, 0, stream>>>(cs, cd, et1, eq1, mask_src, partial, EC, ET, EQ);
    binprefix_kernel<<<dim3(NBIN / 256, 3), 256, 0, stream>>>(partial, cnt);
    scan3_kernel<<<3, 1024, 0, stream>>>(cnt, offs);
    scatter_det<<<dim3(NB, 3), 256, 0, stream>>>(cs, cd, et0, et1, eq0, eq1, partial, offs,
                                                 ids_cd, ids_t, ids_q, EC, ET, EQ);

    colsum_kernel<<<NQ / 128, 256, 0, stream>>>(Xq, Qsum);

    // ---- G12: Xq -> [Aq fp32 | Vqc bf16], Xt -> [At fp32 | Vtc fp32] ----
    GemmJob jq{}, jt{};
    jq.A0 = Xq; jq.W00 = W_ac_q; jq.W01 = W_vc_q; jq.bias0 = b_ac_q; jq.bias1 = b_vc_q;
    jq.C0 = N0; jq.Cb1 = B0; jq.act = 1;
    jt.A0 = Xt; jt.W00 = W_ac_t; jt.W01 = W_vc_t; jt.bias0 = b_ac_t; jt.bias1 = b_vc_t;
    jt.C0 = N1; jt.C1 = N3; jt.act = 1;
    gemm_big<<<dim3(NQ / 128, 4, 2), 256, 0, stream>>>(jq, jt);

    // ---- Xq2t (fused logits + softmax agg, bf16 value gather) -> N4 ----
    seg_agg_cross<<<(NT + 3) / 4, 256, 0, stream>>>(offs_cd, ids_cd, N0, N1,
                                                    (const unsigned int*)B0, N4, NT);

    mt_extra_kernel<<<1, 128, 0, stream>>>(Qsum, W_mt, b_mt, mte, NQ);

    // ---- G56: merged builds ----
    GemmJob mq{}, mt{};
    mq.A0 = Xq; mq.W00 = W_mq;               mq.A1 = N3; mq.W10 = W_mq + 128 * 128;
    mq.rowmask1 = mask_src; mq.bias0 = b_mq; mq.C0 = N2; mq.act = 0;
    mt.A0 = Xt; mt.W00 = W_mt;               mt.A1 = N4; mt.W10 = W_mt + 128 * 128;
    mt.bias0 = mte; mt.C0 = N1; mt.act = 0;
    gemm_big<<<dim3(NQ / 128, 2, 2), 256, 0, stream>>>(mq, mt);

    // ---- attention score vectors ----
    gemv2_kernel<<<(NT + NQ) / 4, 256, 0, stream>>>(N1, W_at, st0v, NT, N2, W_aq, sq0v, NQ);

    // ---- G34: N1 -> [Ut bf16 | Vt fp32], N2 -> [Uq bf16 | Vq fp32] ----
    GemmJob ut{}, uq{};
    ut.A0 = N1; ut.W00 = W_vt; ut.W01 = W_vt + 128 * 128; ut.Cb0 = B1; ut.C1 = Xt_out; ut.act = 0;
    uq.A0 = N2; uq.W00 = W_vq; uq.W01 = W_vq + 128 * 128; uq.Cb0 = B2; uq.C1 = Xq_out; uq.act = 0;
    gemm_big<<<dim3(NT / 128, 4, 2), 256, 0, stream>>>(ut, uq);

    // ---- final intra aggregations (fused t+q, bf16 U gathers) ----
    seg_agg_intra<<<dim3((NT + 3) / 4, 2), 256, 0, stream>>>(
        offs_t, ids_t, st0v, (const unsigned int*)B1, Xt_out, b_vt, Xt_out,
        offs_q, ids_q, sq0v, (const unsigned int*)B2, Xq_out, b_vq, Xq_out, NT);
}

// Round 5
// 269.195 us; speedup vs baseline: 1.8633x; 1.0262x over previous
//
#include <hip/hip_runtime.h>
#include <math.h>

// ---------------------------------------------------------------------------
// OurGMNCustom round 5.
// Math simplifications (validated: absmax 3.9e-3 vs 2e-2 threshold):
//  * Xt2q[q] = elu(Xt@Wvc_t+b)[q] * [deg_cross_src(q)>0]
//  * intra msg@Wv = U[e0]+V[e1]+b ; V[e1]+b segment-constant
//  * intra attention logit: only s0[e0] matters
//  * Q-mean term folded into bias
// Round-5 changes:
//  * Aq/At logit tables stored f16 (sole consumer = cross dots); pass-1 dot
//    uses v_dot2_f32_f16 (fp32 accum) -> half the gather bytes + instrs.
//  * gemv fused into G56 epilogue (per-block partial dots + atomicAdd).
//  * mt_extra parallelized (512 thr, split-k) - was a serial-chain 1-blocker.
// ---------------------------------------------------------------------------

#define NBIN 8192          // == NQ == NT for this problem
#define NB   128           // histogram blocks per array
#define DEGCAP 256         // per-segment LDS logit cache (cross, deg>64 path)

typedef _Float16 h2f __attribute__((ext_vector_type(2)));

__device__ __forceinline__ float elu1(float x) { return x > 0.f ? x : __expf(x) - 1.f; }

__device__ __forceinline__ unsigned short f2bf(float x) {
    unsigned u = __float_as_uint(x);
    u += 0x7FFF + ((u >> 16) & 1);          // round-to-nearest-even
    return (unsigned short)(u >> 16);
}
__device__ __forceinline__ float bflo(unsigned u) { return __uint_as_float(u << 16); }
__device__ __forceinline__ float bfhi(unsigned u) { return __uint_as_float(u & 0xFFFF0000u); }
__device__ __forceinline__ unsigned short f2h(float x) {
    return __builtin_bit_cast(unsigned short, (_Float16)x);
}

// 8 dims of an f16 dot (fp32 accumulate)
__device__ __forceinline__ float dot8_f16(const uint4 a, const uint4 b, float d) {
#if __has_builtin(__builtin_amdgcn_fdot2)
    d = __builtin_amdgcn_fdot2(__builtin_bit_cast(h2f, a.x), __builtin_bit_cast(h2f, b.x), d, false);
    d = __builtin_amdgcn_fdot2(__builtin_bit_cast(h2f, a.y), __builtin_bit_cast(h2f, b.y), d, false);
    d = __builtin_amdgcn_fdot2(__builtin_bit_cast(h2f, a.z), __builtin_bit_cast(h2f, b.z), d, false);
    d = __builtin_amdgcn_fdot2(__builtin_bit_cast(h2f, a.w), __builtin_bit_cast(h2f, b.w), d, false);
#else
    const unsigned ua[4] = { a.x, a.y, a.z, a.w };
    const unsigned ub[4] = { b.x, b.y, b.z, b.w };
    #pragma unroll
    for (int t = 0; t < 4; ++t) {
        const h2f ha = __builtin_bit_cast(h2f, ua[t]);
        const h2f hb = __builtin_bit_cast(h2f, ub[t]);
        d = fmaf((float)ha.x, (float)hb.x, d);
        d = fmaf((float)ha.y, (float)hb.y, d);
    }
#endif
    return d;
}

// ------------------------- fused GEMM --------------------------------------
// Per output, exactly one of {C (fp32), Cb (bf16), Ch (f16)} non-null.
// gvw/gvo: optional fused row-dot (gemv) with atomicAdd into gvo (out0 only).
struct GemmJob {
    const float* A0; const float* A1; const int* rowmask1;
    const float* W00; const float* W01;
    const float* W10; const float* W11;
    const float* bias0; const float* bias1;
    float* C0; float* C1;
    unsigned short* Cb0; unsigned short* Cb1;
    unsigned short* Ch0; unsigned short* Ch1;
    const float* gvw; float* gvo;
    int act;
};

__global__ __launch_bounds__(256) void gemm_big(GemmJob j0, GemmJob j1)
{
    const GemmJob j = blockIdx.z ? j1 : j0;
    const int out = blockIdx.y >> 1;
    const int c0 = (blockIdx.y & 1) * 64;
    const int r0 = blockIdx.x * 128;
    __shared__ float As[32][132];
    __shared__ float Ws[32][64];
    const int tid = threadIdx.x;
    const int tr = tid >> 4, tc = tid & 15;
    float acc[8][4] = {};

    const float* A_pass[2] = { j.A0, j.A1 };
    const float* W_pass[2] = { out ? j.W01 : j.W00, out ? j.W11 : j.W10 };

    for (int p = 0; p < 2; ++p) {
        const float* A = A_pass[p];
        if (!A) break;
        const float* W = W_pass[p];
        const int* rm = (p == 1) ? j.rowmask1 : nullptr;
        for (int kc = 0; kc < 4; ++kc) {
            {
                const int k4 = (tid & 7) * 4;
                const int rb = tid >> 3;          // 0..31
                #pragma unroll
                for (int i = 0; i < 4; ++i) {
                    const int r = rb + 32 * i;
                    float4 v = *(const float4*)(A + (size_t)(r0 + r) * 128 + kc * 32 + k4);
                    if (rm && rm[r0 + r] == 0) v = make_float4(0.f, 0.f, 0.f, 0.f);
                    As[k4 + 0][r] = v.x; As[k4 + 1][r] = v.y;
                    As[k4 + 2][r] = v.z; As[k4 + 3][r] = v.w;
                }
                const int cc = (tid & 15) * 4;
                const int kb = tid >> 4;          // 0..15
                #pragma unroll
                for (int i = 0; i < 2; ++i) {
                    const int k = kb + 16 * i;
                    *(float4*)&Ws[k][cc] = *(const float4*)(W + (size_t)(kc * 32 + k) * 128 + c0 + cc);
                }
            }
            __syncthreads();
            #pragma unroll 4
            for (int k = 0; k < 32; ++k) {
                const float4 a0 = *(const float4*)&As[k][tr * 4];
                const float4 a1 = *(const float4*)&As[k][64 + tr * 4];
                const float4 w  = *(const float4*)&Ws[k][tc * 4];
                const float ar[8] = {a0.x, a0.y, a0.z, a0.w, a1.x, a1.y, a1.z, a1.w};
                #pragma unroll
                for (int i = 0; i < 8; ++i) {
                    acc[i][0] = fmaf(ar[i], w.x, acc[i][0]);
                    acc[i][1] = fmaf(ar[i], w.y, acc[i][1]);
                    acc[i][2] = fmaf(ar[i], w.z, acc[i][2]);
                    acc[i][3] = fmaf(ar[i], w.w, acc[i][3]);
                }
            }
            __syncthreads();
        }
    }

    float4 bv = make_float4(0.f, 0.f, 0.f, 0.f);
    const float* bias = out ? j.bias1 : j.bias0;
    if (bias) bv = *(const float4*)(bias + c0 + tc * 4);
    float* C = out ? j.C1 : j.C0;
    unsigned short* Cb = out ? j.Cb1 : j.Cb0;
    unsigned short* Ch = out ? j.Ch1 : j.Ch0;
    const int dogv = (j.gvw != nullptr) && (out == 0);
    float4 wv4 = make_float4(0.f, 0.f, 0.f, 0.f);
    if (dogv) wv4 = *(const float4*)(j.gvw + c0 + tc * 4);
    float pacc[8];
    #pragma unroll
    for (int i = 0; i < 8; ++i) {
        const int row = r0 + (i >> 2) * 64 + tr * 4 + (i & 3);
        float4 o;
        o.x = acc[i][0] + bv.x; o.y = acc[i][1] + bv.y;
        o.z = acc[i][2] + bv.z; o.w = acc[i][3] + bv.w;
        if (j.act) { o.x = elu1(o.x); o.y = elu1(o.y); o.z = elu1(o.z); o.w = elu1(o.w); }
        pacc[i] = o.x * wv4.x + o.y * wv4.y + o.z * wv4.z + o.w * wv4.w;
        if (C) {
            *(float4*)(C + (size_t)row * 128 + c0 + tc * 4) = o;
        } else if (Cb) {
            uint2 pk;
            pk.x = (unsigned)f2bf(o.x) | ((unsigned)f2bf(o.y) << 16);
            pk.y = (unsigned)f2bf(o.z) | ((unsigned)f2bf(o.w) << 16);
            *(uint2*)(Cb + (size_t)row * 128 + c0 + tc * 4) = pk;
        } else {
            uint2 pk;
            pk.x = (unsigned)f2h(o.x) | ((unsigned)f2h(o.y) << 16);
            pk.y = (unsigned)f2h(o.z) | ((unsigned)f2h(o.w) << 16);
            *(uint2*)(Ch + (size_t)row * 128 + c0 + tc * 4) = pk;
        }
    }
    if (dogv) {
        #pragma unroll
        for (int i = 0; i < 8; ++i) {
            float p = pacc[i];
            p += __shfl_xor(p, 1, 64); p += __shfl_xor(p, 2, 64);
            p += __shfl_xor(p, 4, 64); p += __shfl_xor(p, 8, 64);
            if (tc == 0)
                atomicAdd(j.gvo + r0 + (i >> 2) * 64 + tr * 4 + (i & 3), p);
        }
    }
}

// ------------------------- CSR build (atomic-free, arrays parallel) --------
__global__ __launch_bounds__(256) void hist_priv(
    const int* __restrict__ cs, const int* __restrict__ cd,
    const int* __restrict__ et1, const int* __restrict__ eq1,
    int* __restrict__ mask_src, unsigned short* __restrict__ partial,
    int EC, int ET, int EQ)
{
    __shared__ int h[NBIN];
    const int k = blockIdx.x, a = blockIdx.y, tid = threadIdx.x;
    const int* idxs[3] = { cd, et1, eq1 };
    const int Es[3] = { EC, ET, EQ };
    for (int b = tid; b < NBIN; b += 256) h[b] = 0;
    __syncthreads();
    const int E = Es[a];
    const int per = (E + NB - 1) / NB;
    const int lo = k * per;
    const int hi = min(E, lo + per);
    const int* idx = idxs[a];
    for (int e = lo + tid; e < hi; e += 256) {
        atomicAdd(&h[idx[e]], 1);                 // LDS atomic
        if (a == 0) mask_src[cs[e]] = 1;          // benign race
    }
    __syncthreads();
    unsigned short* P = partial + ((size_t)a * NB + k) * NBIN;
    for (int b = tid; b < NBIN; b += 256) P[b] = (unsigned short)h[b];
}

// fused subsum+subscan+expand: per bin, serial exclusive scan over NB blocks
__global__ void binprefix_kernel(unsigned short* __restrict__ partial, int* __restrict__ cnt)
{
    const int bin = blockIdx.x * 256 + threadIdx.x;
    const int a = blockIdx.y;
    unsigned short* P = partial + (size_t)a * NB * NBIN;
    int s = 0;
    #pragma unroll 4
    for (int k = 0; k < NB; ++k) {
        const int p = P[(size_t)k * NBIN + bin];
        P[(size_t)k * NBIN + bin] = (unsigned short)s;
        s += p;
    }
    cnt[a * NBIN + bin] = s;
}

__global__ __launch_bounds__(1024) void scan3_kernel(const int* __restrict__ cnt, int* __restrict__ offs)
{
    const int b = blockIdx.x;
    const int* c = cnt + (size_t)b * NBIN;
    int* o = offs + (size_t)b * (NBIN + 1);
    __shared__ int sums[1024];
    const int tid = threadIdx.x;
    int loc[8]; int s = 0;
    #pragma unroll
    for (int j = 0; j < 8; ++j) { loc[j] = s; s += c[tid * 8 + j]; }
    sums[tid] = s;
    __syncthreads();
    for (int off = 1; off < 1024; off <<= 1) {
        int v = 0;
        if (tid >= off) v = sums[tid - off];
        __syncthreads();
        sums[tid] += v;
        __syncthreads();
    }
    const int ex = tid ? sums[tid - 1] : 0;
    #pragma unroll
    for (int j = 0; j < 8; ++j) o[tid * 8 + j] = ex + loc[j];
    if (tid == 1023) o[NBIN] = sums[1023];
}

// deterministic scatter (LDS cursors, arrays parallel via blockIdx.y)
__global__ __launch_bounds__(256) void scatter_det(
    const int* __restrict__ cs, const int* __restrict__ cd,
    const int* __restrict__ et0, const int* __restrict__ et1,
    const int* __restrict__ eq0, const int* __restrict__ eq1,
    const unsigned short* __restrict__ partial, const int* __restrict__ offs,
    int* __restrict__ ids_cd, int* __restrict__ ids_t, int* __restrict__ ids_q,
    int EC, int ET, int EQ)
{
    __shared__ int cur[NBIN];
    const int k = blockIdx.x, a = blockIdx.y, tid = threadIdx.x;
    const int Es[3] = { EC, ET, EQ };
    const int* seg[3] = { cd, et1, eq1 };
    const int* pay[3] = { cs, et0, eq0 };
    int* dst[3] = { ids_cd, ids_t, ids_q };
    const unsigned short* P = partial + ((size_t)a * NB + k) * NBIN;
    const int* off = offs + (size_t)a * (NBIN + 1);
    for (int b = tid; b < NBIN; b += 256) cur[b] = off[b] + (int)P[b];
    __syncthreads();
    const int E = Es[a];
    const int per = (E + NB - 1) / NB;
    const int lo = k * per;
    const int hi = min(E, lo + per);
    const int* sg = seg[a]; const int* pl = pay[a]; int* dd = dst[a];
    for (int e = lo + tid; e < hi; e += 256) {
        const int pos = atomicAdd(&cur[sg[e]], 1);    // LDS atomic
        dd[pos] = pl[e];
    }
}

// ------------------------- column sums + folded bias -----------------------
__global__ void colsum_kernel(const float* __restrict__ X, float* __restrict__ sum)
{
    const int c = threadIdx.x & 127;
    const int half = threadIdx.x >> 7;
    float s = 0.f;
    #pragma unroll 8
    for (int j = 0; j < 64; ++j) {
        const int r = blockIdx.x * 128 + half + 2 * j;
        s += X[(size_t)r * 128 + c];
    }
    atomicAdd(&sum[c], s);
}

// mte[c] = b_mt[c] + sum_k (Qsum[k]/M) * W_mt[256+k][c]   (split-k, 512 thr)
__global__ __launch_bounds__(512) void mt_extra_kernel(
    const float* __restrict__ Qsum, const float* __restrict__ Wmt,
    const float* __restrict__ bmt, float* __restrict__ outv, int M)
{
    __shared__ float red[4][128];
    const int c = threadIdx.x & 127, kq = threadIdx.x >> 7;
    const float inv = 1.0f / (float)M;
    float acc = 0.f;
    #pragma unroll 4
    for (int k = kq * 32; k < kq * 32 + 32; ++k)
        acc = fmaf(Qsum[k] * inv, Wmt[(size_t)(256 + k) * 128 + c], acc);
    red[kq][c] = acc;
    __syncthreads();
    if (kq == 0) outv[c] = bmt[c] + red[0][c] + red[1][c] + red[2][c] + red[3][c];
}

// ------------------------- batched weighted bf16 gather core ---------------
__device__ __forceinline__ void gather_chunk_bf(
    const unsigned int* __restrict__ rows, int myid, float wv, int rem,
    int half, int cl, float4& acc)
{
    const int npairs = (rem + 1) >> 1;
    int j = 0;
    for (; j + 4 <= npairs; j += 4) {
        const int e0 = 2 * j + half, e1 = e0 + 2, e2 = e0 + 4, e3 = e0 + 6;
        const int s0 = __shfl(myid, e0, 64); const float w0 = __shfl(wv, e0, 64);
        const int s1 = __shfl(myid, e1, 64); const float w1 = __shfl(wv, e1, 64);
        const int s2 = __shfl(myid, e2, 64); const float w2 = __shfl(wv, e2, 64);
        const int s3 = __shfl(myid, e3, 64); const float w3 = __shfl(wv, e3, 64);
        const uint2 v0 = *(const uint2*)(rows + (size_t)s0 * 64 + cl * 2);
        const uint2 v1 = *(const uint2*)(rows + (size_t)s1 * 64 + cl * 2);
        const uint2 v2 = *(const uint2*)(rows + (size_t)s2 * 64 + cl * 2);
        const uint2 v3 = *(const uint2*)(rows + (size_t)s3 * 64 + cl * 2);
        acc.x = fmaf(w0, bflo(v0.x), acc.x); acc.y = fmaf(w0, bfhi(v0.x), acc.y);
        acc.z = fmaf(w0, bflo(v0.y), acc.z); acc.w = fmaf(w0, bfhi(v0.y), acc.w);
        acc.x = fmaf(w1, bflo(v1.x), acc.x); acc.y = fmaf(w1, bfhi(v1.x), acc.y);
        acc.z = fmaf(w1, bflo(v1.y), acc.z); acc.w = fmaf(w1, bfhi(v1.y), acc.w);
        acc.x = fmaf(w2, bflo(v2.x), acc.x); acc.y = fmaf(w2, bfhi(v2.x), acc.y);
        acc.z = fmaf(w2, bflo(v2.y), acc.z); acc.w = fmaf(w2, bfhi(v2.y), acc.w);
        acc.x = fmaf(w3, bflo(v3.x), acc.x); acc.y = fmaf(w3, bfhi(v3.x), acc.y);
        acc.z = fmaf(w3, bflo(v3.y), acc.z); acc.w = fmaf(w3, bfhi(v3.y), acc.w);
    }
    for (; j < npairs; ++j) {
        const int e = 2 * j + half;
        const int sv = __shfl(myid, e, 64); const float we = __shfl(wv, e, 64);
        const uint2 v = *(const uint2*)(rows + (size_t)sv * 64 + cl * 2);
        acc.x = fmaf(we, bflo(v.x), acc.x); acc.y = fmaf(we, bfhi(v.x), acc.y);
        acc.z = fmaf(we, bflo(v.y), acc.z); acc.w = fmaf(we, bfhi(v.y), acc.w);
    }
}

// ------------------------- intra segment softmax agg (fused t/q) -----------
__global__ __launch_bounds__(256) void seg_agg_intra(
    const int* ot, const int* it, const float* nlt, const unsigned int* rt,
    const float* xt, const float* ebt, float* outt,
    const int* oq, const int* iq, const float* nlq, const unsigned int* rq,
    const float* xq, const float* ebq, float* outq, int nseg)
{
    const int* offs; const int* ids; const float* nl; const unsigned int* rows;
    const float* extra; const float* eb; float* out;
    if (blockIdx.y == 0) { offs = ot; ids = it; nl = nlt; rows = rt; extra = xt; eb = ebt; out = outt; }
    else                 { offs = oq; ids = iq; nl = nlq; rows = rq; extra = xq; eb = ebq; out = outq; }
    const int wid = (int)((blockIdx.x * blockDim.x + threadIdx.x) >> 6);
    const int lane = threadIdx.x & 63;
    if (wid >= nseg) return;
    const int lo = offs[wid], hi = offs[wid + 1];
    const int deg = hi - lo;
    if (deg == 0) {
        *(float2*)(out + (size_t)wid * 128 + lane * 2) = make_float2(0.f, 0.f);
        return;
    }
    const int half = lane >> 5, cl = lane & 31;
    float s;
    float4 acc = make_float4(0.f, 0.f, 0.f, 0.f);
    if (deg <= 64) {                       // fast path: ids/logits in registers
        int myid = 0; float l = -3.4e38f;
        if (lane < deg) { myid = ids[lo + lane]; l = nl[myid]; }
        float m = l;
        #pragma unroll
        for (int t = 32; t; t >>= 1) m = fmaxf(m, __shfl_xor(m, t, 64));
        const float wv = (lane < deg) ? __expf(l - m) : 0.f;
        s = wv;
        gather_chunk_bf(rows, myid, wv, deg, half, cl, acc);
    } else {
        float m = -3.4e38f;
        for (int i = lo + lane; i < hi; i += 64) m = fmaxf(m, nl[ids[i]]);
        #pragma unroll
        for (int t = 32; t; t >>= 1) m = fmaxf(m, __shfl_xor(m, t, 64));
        s = 0.f;
        for (int base = lo; base < hi; base += 64) {
            const int rem = min(64, hi - base);
            int myid = 0; float wv = 0.f;
            if (lane < rem) { myid = ids[base + lane]; wv = __expf(nl[myid] - m); }
            s += wv;
            gather_chunk_bf(rows, myid, wv, rem, half, cl, acc);
        }
    }
    #pragma unroll
    for (int t = 32; t; t >>= 1) s += __shfl_xor(s, t, 64);
    acc.x += __shfl_xor(acc.x, 32, 64); acc.y += __shfl_xor(acc.y, 32, 64);
    acc.z += __shfl_xor(acc.z, 32, 64); acc.w += __shfl_xor(acc.w, 32, 64);
    if (half == 0) {
        const float inv = 1.f / s;
        const float4 xv = *(const float4*)(extra + (size_t)wid * 128 + cl * 4);
        const float4 bv = *(const float4*)(eb + cl * 4);
        float4 o;
        o.x = fmaf(acc.x, inv, xv.x + bv.x);
        o.y = fmaf(acc.y, inv, xv.y + bv.y);
        o.z = fmaf(acc.z, inv, xv.z + bv.z);
        o.w = fmaf(acc.w, inv, xv.w + bv.w);
        *(float4*)(out + (size_t)wid * 128 + cl * 4) = o;
    }
}

// ------------------------- cross: fused logits + softmax agg ---------------
// segment = dst node (t). logit_e = dot_f16(Aqh[src_e], Ath[dst]) in fp32
// accum; value gather (Vq) in bf16.
__global__ __launch_bounds__(256) void seg_agg_cross(
    const int* __restrict__ offs, const int* __restrict__ ids,
    const unsigned int* __restrict__ Aqh, const unsigned int* __restrict__ Ath,
    const unsigned int* __restrict__ Vqb, float* __restrict__ out, int nseg)
{
    __shared__ unsigned int atrowh[4][64];
    __shared__ float lcache[4][DEGCAP];
    const int w = threadIdx.x >> 6;
    const int lane = threadIdx.x & 63;
    const int wid = blockIdx.x * 4 + w;
    if (wid >= nseg) return;
    const int lo = offs[wid], hi = offs[wid + 1];
    const int deg = hi - lo;
    if (deg == 0) {
        *(float2*)(out + (size_t)wid * 128 + lane * 2) = make_float2(0.f, 0.f);
        return;
    }
    atrowh[w][lane] = Ath[(size_t)wid * 64 + lane];
    __threadfence_block();

    const int half = lane >> 5, cl = lane & 31;
    float s;
    float4 acc = make_float4(0.f, 0.f, 0.f, 0.f);

    if (deg <= 64) {                       // fast path: dot kept in register
        int myid = 0; float d = -3.4e38f;
        if (lane < deg) {
            myid = ids[lo + lane];
            const unsigned int* ar = Aqh + (size_t)myid * 64;
            d = 0.f;
            #pragma unroll
            for (int k = 0; k < 64; k += 4)
                d = dot8_f16(*(const uint4*)(ar + k), *(const uint4*)&atrowh[w][k], d);
        }
        float m = d;
        #pragma unroll
        for (int t = 32; t; t >>= 1) m = fmaxf(m, __shfl_xor(m, t, 64));
        const float wv = (lane < deg) ? __expf(d - m) : 0.f;
        s = wv;
        gather_chunk_bf(Vqb, myid, wv, deg, half, cl, acc);
    } else {
        float m = -3.4e38f;
        for (int base = lo; base < hi; base += 64) {
            const int i = base + lane;
            if (i < hi) {
                const int src = ids[i];
                const unsigned int* ar = Aqh + (size_t)src * 64;
                float d = 0.f;
                #pragma unroll
                for (int k = 0; k < 64; k += 4)
                    d = dot8_f16(*(const uint4*)(ar + k), *(const uint4*)&atrowh[w][k], d);
                const int li = i - lo;
                if (li < DEGCAP) lcache[w][li] = d;
                m = fmaxf(m, d);
            }
        }
        #pragma unroll
        for (int t = 32; t; t >>= 1) m = fmaxf(m, __shfl_xor(m, t, 64));
        __threadfence_block();
        s = 0.f;
        for (int base = lo; base < hi; base += 64) {
            const int rem = min(64, hi - base);
            int myid = 0; float wv = 0.f;
            if (lane < rem) {
                myid = ids[base + lane];
                const int li = base - lo + lane;
                float d;
                if (li < DEGCAP) d = lcache[w][li];
                else {
                    const unsigned int* ar = Aqh + (size_t)myid * 64;
                    d = 0.f;
                    for (int k = 0; k < 64; k += 4)
                        d = dot8_f16(*(const uint4*)(ar + k), *(const uint4*)&atrowh[w][k], d);
                }
                wv = __expf(d - m);
            }
            s += wv;
            gather_chunk_bf(Vqb, myid, wv, rem, half, cl, acc);
        }
    }
    #pragma unroll
    for (int t = 32; t; t >>= 1) s += __shfl_xor(s, t, 64);
    acc.x += __shfl_xor(acc.x, 32, 64); acc.y += __shfl_xor(acc.y, 32, 64);
    acc.z += __shfl_xor(acc.z, 32, 64); acc.w += __shfl_xor(acc.w, 32, 64);
    if (half == 0) {
        const float inv = 1.f / s;
        float4 o;
        o.x = acc.x * inv; o.y = acc.y * inv; o.z = acc.z * inv; o.w = acc.w * inv;
        *(float4*)(out + (size_t)wid * 128 + cl * 4) = o;
    }
}

// ---------------------------------------------------------------------------
extern "C" void kernel_launch(void* const* d_in, const int* in_sizes, int n_in,
                              void* d_out, int out_size, void* d_ws, size_t ws_size,
                              hipStream_t stream)
{
    const float* Xq    = (const float*)d_in[0];
    const int*   eqidx = (const int*)d_in[1];
    const float* Xt    = (const float*)d_in[2];
    const int*   etidx = (const int*)d_in[3];
    const int*   cs    = (const int*)d_in[6];
    const int*   cd    = (const int*)d_in[7];
    const float* W_ac_q = (const float*)d_in[10]; const float* b_ac_q = (const float*)d_in[11];
    const float* W_ac_t = (const float*)d_in[12]; const float* b_ac_t = (const float*)d_in[13];
    const float* W_vc_q = (const float*)d_in[14]; const float* b_vc_q = (const float*)d_in[15];
    const float* W_vc_t = (const float*)d_in[16]; const float* b_vc_t = (const float*)d_in[17];
    const float* W_mq   = (const float*)d_in[18]; const float* b_mq   = (const float*)d_in[19];
    const float* W_mt   = (const float*)d_in[20]; const float* b_mt   = (const float*)d_in[21];
    const float* W_aq   = (const float*)d_in[22];
    const float* W_vq   = (const float*)d_in[24]; const float* b_vq   = (const float*)d_in[25];
    const float* W_at   = (const float*)d_in[26];
    const float* W_vt   = (const float*)d_in[28]; const float* b_vt   = (const float*)d_in[29];

    const int NQ = in_sizes[0] / 128;
    const int EQ = in_sizes[1] / 2;
    const int NT = in_sizes[2] / 128;
    const int ET = in_sizes[3] / 2;
    const int EC = in_sizes[6];

    const int* eq0 = eqidx;  const int* eq1 = eqidx + EQ;
    const int* et0 = etidx;  const int* et1 = etidx + ET;

    // ------------- workspace bump allocator --------------------------------
    float* base = (float*)d_ws;
    size_t off = 0;
    auto alloc = [&](size_t n) { float* p = base + off; off += n; return p; };
    float* N1 = alloc((size_t)NT * 128);   // Xt_merged
    float* N2 = alloc((size_t)NQ * 128);   // Xq_merged
    float* N3 = alloc((size_t)NT * 128);   // Vtc (fp32)
    float* N4 = alloc((size_t)NT * 128);   // Xq2t
    unsigned int* A0h = (unsigned int*)alloc((size_t)NQ * 64);    // Aq f16
    unsigned int* A1h = (unsigned int*)alloc((size_t)NT * 64);    // At f16
    unsigned short* B0 = (unsigned short*)alloc((size_t)NQ * 64); // Vqc bf16
    unsigned short* B1 = (unsigned short*)alloc((size_t)NT * 64); // Ut  bf16
    unsigned short* B2 = (unsigned short*)alloc((size_t)NQ * 64); // Uq  bf16
    float* mte  = alloc(128);
    // ---- memset region: st0v, sq0v, mask_src, Qsum contiguous ----
    float* st0v = alloc((size_t)NT);
    float* sq0v = alloc((size_t)NQ);
    int* mask_src = (int*)alloc((size_t)NQ);
    float* Qsum   = alloc(128);
    const size_t zero_bytes = ((size_t)NT + NQ + NQ + 128) * 4;
    int* cnt  = (int*)alloc((size_t)3 * NBIN);
    int* offs = (int*)alloc((size_t)3 * (NBIN + 1));
    unsigned short* partial = (unsigned short*)alloc((size_t)3 * NB * NBIN / 2);
    int* ids_cd = (int*)alloc((size_t)EC);
    int* ids_t  = (int*)alloc((size_t)ET);
    int* ids_q  = (int*)alloc((size_t)EQ);

    float* Xq_out = (float*)d_out;
    float* Xt_out = (float*)d_out + (size_t)NQ * 128;

    const int* offs_cd = offs;
    const int* offs_t  = offs + (NBIN + 1);
    const int* offs_q  = offs + 2 * (NBIN + 1);

    hipMemsetAsync(st0v, 0, zero_bytes, stream);

    // ---- CSR build (atomic-free) ----
    hist_priv<<<dim3(NB, 3), 256, 0, stream>>>(cs, cd, et1, eq1, mask_src, partial, EC, ET, EQ);
    binprefix_kernel<<<dim3(NBIN / 256, 3), 256, 0, stream>>>(partial, cnt);
    scan3_kernel<<<3, 1024, 0, stream>>>(cnt, offs);
    scatter_det<<<dim3(NB, 3), 256, 0, stream>>>(cs, cd, et0, et1, eq0, eq1, partial, offs,
                                                 ids_cd, ids_t, ids_q, EC, ET, EQ);

    colsum_kernel<<<NQ / 128, 256, 0, stream>>>(Xq, Qsum);
    mt_extra_kernel<<<1, 512, 0, stream>>>(Qsum, W_mt, b_mt, mte, NQ);

    // ---- G12: Xq -> [Aq f16 | Vqc bf16], Xt -> [At f16 | Vtc fp32] ----
    GemmJob jq{}, jt{};
    jq.A0 = Xq; jq.W00 = W_ac_q; jq.W01 = W_vc_q; jq.bias0 = b_ac_q; jq.bias1 = b_vc_q;
    jq.Ch0 = (unsigned short*)A0h; jq.Cb1 = B0; jq.act = 1;
    jt.A0 = Xt; jt.W00 = W_ac_t; jt.W01 = W_vc_t; jt.bias0 = b_ac_t; jt.bias1 = b_vc_t;
    jt.Ch0 = (unsigned short*)A1h; jt.C1 = N3; jt.act = 1;
    gemm_big<<<dim3(NQ / 128, 4, 2), 256, 0, stream>>>(jq, jt);

    // ---- Xq2t (fused f16 logits + softmax agg, bf16 value gather) -> N4 ----
    seg_agg_cross<<<(NT + 3) / 4, 256, 0, stream>>>(offs_cd, ids_cd, A0h, A1h,
                                                    (const unsigned int*)B0, N4, NT);

    // ---- G56: merged builds + fused gemv (attention scores) ----
    GemmJob mq{}, mt{};
    mq.A0 = Xq; mq.W00 = W_mq;               mq.A1 = N3; mq.W10 = W_mq + 128 * 128;
    mq.rowmask1 = mask_src; mq.bias0 = b_mq; mq.C0 = N2;
    mq.gvw = W_aq; mq.gvo = sq0v; mq.act = 0;
    mt.A0 = Xt; mt.W00 = W_mt;               mt.A1 = N4; mt.W10 = W_mt + 128 * 128;
    mt.bias0 = mte; mt.C0 = N1;
    mt.gvw = W_at; mt.gvo = st0v; mt.act = 0;
    gemm_big<<<dim3(NQ / 128, 2, 2), 256, 0, stream>>>(mq, mt);

    // ---- G34: N1 -> [Ut bf16 | Vt fp32], N2 -> [Uq bf16 | Vq fp32] ----
    GemmJob ut{}, uq{};
    ut.A0 = N1; ut.W00 = W_vt; ut.W01 = W_vt + 128 * 128; ut.Cb0 = B1; ut.C1 = Xt_out; ut.act = 0;
    uq.A0 = N2; uq.W00 = W_vq; uq.W01 = W_vq + 128 * 128; uq.Cb0 = B2; uq.C1 = Xq_out; uq.act = 0;
    gemm_big<<<dim3(NT / 128, 4, 2), 256, 0, stream>>>(ut, uq);

    // ---- final intra aggregations (fused t+q, bf16 U gathers) ----
    seg_agg_intra<<<dim3((NT + 3) / 4, 2), 256, 0, stream>>>(
        offs_t, ids_t, st0v, (const unsigned int*)B1, Xt_out, b_vt, Xt_out,
        offs_q, ids_q, sq0v, (const unsigned int*)B2, Xq_out, b_vq, Xq_out, NT);
}